// Round 5
// baseline (2081.569 us; speedup 1.0000x reference)
//
#include <hip/hip_runtime.h>
#include <hip/hip_bf16.h>

// ProteinGNNTransformer — all-f32 baseline (inputs/outputs are float32 per the
// reference; earlier NaNs came from misreading f32 buffers as bf16).
// Workspace ~37 MB: qkv buffer aliased with FFN hidden buffer (disjoint live ranges).
// (2nd resubmission — rounds 3 and 4 both died with UnresponsiveContainer
// at connection setup; kernel never ran.)

#define NPROT 3000
#define NAA   25
#define NPROP 1071
#define NTOT  4096
#define DIM   256
#define NH    8
#define DHD   32
#define FFD   1024
#define NEDGE 131072
#define LNEPS 1e-5f

// ---------------- embedding concat: cur = total = concat(pe,ae,qe) ----------------
__global__ __launch_bounds__(256) void k_embed(const float* __restrict__ pe, const float* __restrict__ ae,
                                               const float* __restrict__ qe,
                                               float* __restrict__ cur, float* __restrict__ tot){
  int i = blockIdx.x*256 + threadIdx.x;   // grid covers exactly NTOT*DIM
  int row = i >> 8;
  float v;
  if (row < NPROT)           v = pe[i];
  else if (row < NPROT+NAA)  v = ae[i - NPROT*DIM];
  else                       v = qe[i - (NPROT+NAA)*DIM];
  cur[i] = v; tot[i] = v;
}

__global__ __launch_bounds__(256) void k_zero(int* __restrict__ p, int n){
  int i = blockIdx.x*256 + threadIdx.x; if (i < n) p[i] = 0;
}

// ---------------- CSR build ----------------
__global__ __launch_bounds__(256) void k_hist(const int* __restrict__ rows, int* __restrict__ cnt){
  int e = blockIdx.x*256 + threadIdx.x; if (e < NEDGE) atomicAdd(&cnt[rows[e]], 1);
}

// single-wave chunk scan: lane L owns rows [64L, 64L+64)
__global__ __launch_bounds__(64) void k_scan(const int* __restrict__ cnt, int* __restrict__ rowptr,
                                             int* __restrict__ cursor){
  int lane = threadIdx.x;
  int sum = 0;
  for (int i = 0; i < 64; ++i) sum += cnt[lane*64 + i];
  int pref = sum;
  #pragma unroll
  for (int off = 1; off < 64; off <<= 1){
    int u = __shfl_up(pref, off);
    if (lane >= off) pref += u;
  }
  int run = pref - sum;                   // exclusive prefix of this chunk
  for (int i = 0; i < 64; ++i){
    int c = cnt[lane*64 + i];
    rowptr[lane*64 + i] = run;
    cursor[lane*64 + i] = run;
    run += c;
  }
  if (lane == 63) rowptr[NTOT] = run;
}

__global__ __launch_bounds__(256) void k_scatter(const int* __restrict__ rows, const int* __restrict__ cols,
                                                 const float* __restrict__ vals, int* __restrict__ cursor,
                                                 int* __restrict__ ccol, float* __restrict__ cval){
  int e = blockIdx.x*256 + threadIdx.x; if (e >= NEDGE) return;
  int p = atomicAdd(&cursor[rows[e]], 1);
  ccol[p] = cols[e]; cval[p] = vals[e];
}

// ---------------- SpMM: one block (256 thr) per row ----------------
__global__ __launch_bounds__(256) void k_spmm(const int* __restrict__ rowptr, const int* __restrict__ ccol,
                                              const float* __restrict__ cval, const float* __restrict__ x,
                                              float* __restrict__ out){
  int r = blockIdx.x, c = threadIdx.x;
  int s = rowptr[r], e = rowptr[r+1];
  float acc = 0.f;
  for (int i = s; i < e; ++i)
    acc += cval[i] * x[((size_t)ccol[i] << 8) + c];
  out[((size_t)r << 8) + c] = acc;
}

// ---------------- tiled GEMM: C[M,Nc] = A @ W (+bias)(+relu), all f32 ----------------
template<int RELU, int BIAS>
__global__ __launch_bounds__(256) void k_gemm(const float* __restrict__ A, const float* __restrict__ W,
                                              const float* __restrict__ bias, float* __restrict__ C,
                                              int M, int K, int Nc){
  __shared__ float As[16][65];
  __shared__ float Ws[16][65];
  const int tid = threadIdx.x;
  const int tx = tid & 15, ty = tid >> 4;
  const int row0 = blockIdx.y * 64, col0 = blockIdx.x * 64;
  float acc[4][4] = {};
  for (int k0 = 0; k0 < K; k0 += 16){
    #pragma unroll
    for (int j = 0; j < 4; ++j){
      int idx = tid*4 + j;                       // m = idx>>4, kk = idx&15
      As[idx & 15][idx >> 4] = A[(size_t)(row0 + (idx >> 4))*K + k0 + (idx & 15)];
    }
    #pragma unroll
    for (int j = 0; j < 4; ++j){
      int idx = tid*4 + j;                       // kk = idx>>6, n = idx&63
      Ws[idx >> 6][idx & 63] = W[(size_t)(k0 + (idx >> 6))*Nc + col0 + (idx & 63)];
    }
    __syncthreads();
    #pragma unroll
    for (int kk = 0; kk < 16; ++kk){
      float a0 = As[kk][ty*4+0], a1 = As[kk][ty*4+1], a2 = As[kk][ty*4+2], a3 = As[kk][ty*4+3];
      float w0 = Ws[kk][tx*4+0], w1 = Ws[kk][tx*4+1], w2 = Ws[kk][tx*4+2], w3 = Ws[kk][tx*4+3];
      acc[0][0]+=a0*w0; acc[0][1]+=a0*w1; acc[0][2]+=a0*w2; acc[0][3]+=a0*w3;
      acc[1][0]+=a1*w0; acc[1][1]+=a1*w1; acc[1][2]+=a1*w2; acc[1][3]+=a1*w3;
      acc[2][0]+=a2*w0; acc[2][1]+=a2*w1; acc[2][2]+=a2*w2; acc[2][3]+=a2*w3;
      acc[3][0]+=a3*w0; acc[3][1]+=a3*w1; acc[3][2]+=a3*w2; acc[3][3]+=a3*w3;
    }
    __syncthreads();
  }
  #pragma unroll
  for (int i = 0; i < 4; ++i){
    #pragma unroll
    for (int j = 0; j < 4; ++j){
      float v = acc[i][j];
      if (BIAS) v += bias[col0 + tx*4 + j];
      if (RELU) v = fmaxf(v, 0.f);
      C[(size_t)(row0 + ty*4 + i)*Nc + col0 + tx*4 + j] = v;
    }
  }
}

// ---------------- flash attention (fp32), Q-tile 64, KV-tile 64 ----------------
__global__ __launch_bounds__(256) void k_attn(const float* __restrict__ qkv, float* __restrict__ o){
  __shared__ float Qs[64][DHD+1];
  __shared__ float Ks[64][DHD+1];
  __shared__ float Vs[64][DHD+1];
  __shared__ float Ss[64][65];
  __shared__ float mrow[64], lrow[64], fac[64];
  __shared__ float red[4][64];
  const int h  = blockIdx.y;
  const int q0 = blockIdx.x * 64;
  const int tid = threadIdx.x;
  const int tx = tid & 15, ty = tid >> 4;

  for (int idx = tid; idx < 64*DHD; idx += 256){
    int r = idx >> 5, d = idx & 31;
    Qs[r][d] = qkv[(size_t)(q0 + r)*768 + h*DHD + d] * 0.17677669529663687f; // 1/sqrt(32)
  }
  if (tid < 64){ mrow[tid] = -1.0e30f; lrow[tid] = 0.f; }
  float oa[4][2] = {};
  __syncthreads();

  for (int k0 = 0; k0 < NTOT; k0 += 64){
    for (int idx = tid; idx < 64*DHD; idx += 256){
      int r = idx >> 5, d = idx & 31;
      Ks[r][d] = qkv[(size_t)(k0 + r)*768 + 256 + h*DHD + d];
      Vs[r][d] = qkv[(size_t)(k0 + r)*768 + 512 + h*DHD + d];
    }
    __syncthreads();

    // S = Qs @ Ks^T  (each thread: 4x4 micro-tile)
    float sa[4][4] = {};
    #pragma unroll 4
    for (int d = 0; d < DHD; ++d){
      float a0 = Qs[ty*4+0][d], a1 = Qs[ty*4+1][d], a2 = Qs[ty*4+2][d], a3 = Qs[ty*4+3][d];
      float b0 = Ks[tx*4+0][d], b1 = Ks[tx*4+1][d], b2 = Ks[tx*4+2][d], b3 = Ks[tx*4+3][d];
      sa[0][0]+=a0*b0; sa[0][1]+=a0*b1; sa[0][2]+=a0*b2; sa[0][3]+=a0*b3;
      sa[1][0]+=a1*b0; sa[1][1]+=a1*b1; sa[1][2]+=a1*b2; sa[1][3]+=a1*b3;
      sa[2][0]+=a2*b0; sa[2][1]+=a2*b1; sa[2][2]+=a2*b2; sa[2][3]+=a2*b3;
      sa[3][0]+=a3*b0; sa[3][1]+=a3*b1; sa[3][2]+=a3*b2; sa[3][3]+=a3*b3;
    }
    #pragma unroll
    for (int i = 0; i < 4; ++i)
      #pragma unroll
      for (int j = 0; j < 4; ++j)
        Ss[ty*4+i][tx*4+j] = sa[i][j];
    __syncthreads();

    // online softmax
    const int seg = tid >> 6, rr = tid & 63;
    float pm = -1.0e30f;
    #pragma unroll
    for (int c2 = 0; c2 < 16; ++c2) pm = fmaxf(pm, Ss[rr][seg*16 + c2]);
    red[seg][rr] = pm;
    __syncthreads();
    if (tid < 64){
      float mt = fmaxf(fmaxf(red[0][tid], red[1][tid]), fmaxf(red[2][tid], red[3][tid]));
      float mn = fmaxf(mrow[tid], mt);
      fac[tid] = __expf(mrow[tid] - mn);
      mrow[tid] = mn;
    }
    __syncthreads();
    float ps = 0.f;
    #pragma unroll
    for (int c2 = 0; c2 < 16; ++c2){
      float p = __expf(Ss[rr][seg*16 + c2] - mrow[rr]);
      Ss[rr][seg*16 + c2] = p;
      ps += p;
    }
    red[seg][rr] = ps;
    __syncthreads();
    if (tid < 64)
      lrow[tid] = lrow[tid]*fac[tid] + red[0][tid] + red[1][tid] + red[2][tid] + red[3][tid];

    // O = O*fac + P @ V   (each thread: 4 rows x 2 cols)
    float f0 = fac[ty*4+0], f1 = fac[ty*4+1], f2 = fac[ty*4+2], f3 = fac[ty*4+3];
    oa[0][0]*=f0; oa[0][1]*=f0;
    oa[1][0]*=f1; oa[1][1]*=f1;
    oa[2][0]*=f2; oa[2][1]*=f2;
    oa[3][0]*=f3; oa[3][1]*=f3;
    #pragma unroll 8
    for (int kk = 0; kk < 64; ++kk){
      float v0 = Vs[kk][tx*2+0], v1 = Vs[kk][tx*2+1];
      float p0 = Ss[ty*4+0][kk], p1 = Ss[ty*4+1][kk], p2 = Ss[ty*4+2][kk], p3 = Ss[ty*4+3][kk];
      oa[0][0]+=p0*v0; oa[0][1]+=p0*v1;
      oa[1][0]+=p1*v0; oa[1][1]+=p1*v1;
      oa[2][0]+=p2*v0; oa[2][1]+=p2*v1;
      oa[3][0]+=p3*v0; oa[3][1]+=p3*v1;
    }
    __syncthreads();
  }

  float li0 = 1.f/lrow[ty*4+0], li1 = 1.f/lrow[ty*4+1], li2 = 1.f/lrow[ty*4+2], li3 = 1.f/lrow[ty*4+3];
  o[(size_t)(q0+ty*4+0)*DIM + h*DHD + tx*2+0] = oa[0][0]*li0;
  o[(size_t)(q0+ty*4+0)*DIM + h*DHD + tx*2+1] = oa[0][1]*li0;
  o[(size_t)(q0+ty*4+1)*DIM + h*DHD + tx*2+0] = oa[1][0]*li1;
  o[(size_t)(q0+ty*4+1)*DIM + h*DHD + tx*2+1] = oa[1][1]*li1;
  o[(size_t)(q0+ty*4+2)*DIM + h*DHD + tx*2+0] = oa[2][0]*li2;
  o[(size_t)(q0+ty*4+2)*DIM + h*DHD + tx*2+1] = oa[2][1]*li2;
  o[(size_t)(q0+ty*4+3)*DIM + h*DHD + tx*2+0] = oa[3][0]*li3;
  o[(size_t)(q0+ty*4+3)*DIM + h*DHD + tx*2+1] = oa[3][1]*li3;
}

// ---------------- fused residual + LayerNorm: out = LN(a+b)*g + be ----------------
__global__ __launch_bounds__(256) void k_add_ln(const float* __restrict__ a, const float* __restrict__ b,
                                                const float* __restrict__ g, const float* __restrict__ be,
                                                float* __restrict__ out){
  __shared__ float red[4];
  int r = blockIdx.x, c = threadIdx.x;
  float v = a[((size_t)r << 8) + c] + b[((size_t)r << 8) + c];
  float s = v;
  #pragma unroll
  for (int off = 32; off; off >>= 1) s += __shfl_down(s, off);
  if ((c & 63) == 0) red[c >> 6] = s;
  __syncthreads();
  float mean = (red[0]+red[1]+red[2]+red[3]) * (1.f/DIM);
  __syncthreads();
  float d = v - mean;
  float s2 = d*d;
  #pragma unroll
  for (int off = 32; off; off >>= 1) s2 += __shfl_down(s2, off);
  if ((c & 63) == 0) red[c >> 6] = s2;
  __syncthreads();
  float var = (red[0]+red[1]+red[2]+red[3]) * (1.f/DIM);
  out[((size_t)r << 8) + c] = d * rsqrtf(var + LNEPS) * g[c] + be[c];
}

// ---------------- cur += x2; total += cur ----------------
__global__ __launch_bounds__(256) void k_update(const float* __restrict__ x2, float* __restrict__ cur,
                                                float* __restrict__ tot){
  int i = blockIdx.x*256 + threadIdx.x;
  float c = cur[i] + x2[i];
  cur[i] = c;
  tot[i] += c;
}

// ---------------- write output: [total | total] as f32 ----------------
__global__ __launch_bounds__(256) void k_out(const float* __restrict__ tot, float* __restrict__ out){
  int i = blockIdx.x*256 + threadIdx.x;
  float v = tot[i];
  out[i] = v;
  out[NTOT*DIM + i] = v;
}

extern "C" void kernel_launch(void* const* d_in, const int* in_sizes, int n_in,
                              void* d_out, int out_size, void* d_ws, size_t ws_size,
                              hipStream_t stream){
  const int*   adj_row = (const int*)  d_in[0];
  const int*   adj_col = (const int*)  d_in[1];
  const float* adj_val = (const float*)d_in[2];
  const float* pe   = (const float*)d_in[3];
  const float* ae   = (const float*)d_in[4];
  const float* qe   = (const float*)d_in[5];
  const float* Wqkv = (const float*)d_in[6];
  const float* Wo   = (const float*)d_in[7];
  const float* W1   = (const float*)d_in[8];
  const float* b1   = (const float*)d_in[9];
  const float* W2   = (const float*)d_in[10];
  const float* b2   = (const float*)d_in[11];
  const float* g1   = (const float*)d_in[12];
  const float* be1  = (const float*)d_in[13];
  const float* g2   = (const float*)d_in[14];
  const float* be2  = (const float*)d_in[15];
  float* out = (float*)d_out;

  // workspace layout — ~37 MB (qkv aliased with FFN hidden: disjoint live ranges)
  char* w = (char*)d_ws;
  float* cur  = (float*)w; w += (size_t)NTOT*DIM*4;       // 4 MB
  float* tot  = (float*)w; w += (size_t)NTOT*DIM*4;       // 4 MB
  float* tb   = (float*)w; w += (size_t)NTOT*DIM*4;       // 4 MB  (spmm out t / x2)
  float* ob   = (float*)w; w += (size_t)NTOT*DIM*4;       // 4 MB  (attn o / x1)
  float* pb   = (float*)w; w += (size_t)NTOT*DIM*4;       // 4 MB  (proj / ffn2 out)
  float* qkvb = (float*)w;                                 // 12 MB (alias)
  float* hb   = (float*)w; w += (size_t)NTOT*FFD*4;       // 16 MB (union with qkvb)
  int* rowptr = (int*)w;   w += (size_t)(NTOT+1)*4;
  int* cnt    = (int*)w;   w += (size_t)NTOT*4;
  int* cursor = (int*)w;   w += (size_t)NTOT*4;
  int* ccol   = (int*)w;   w += (size_t)NEDGE*4;
  float* cval = (float*)w; w += (size_t)NEDGE*4;

  // CSR build (rebuilt deterministically every launch)
  k_zero<<<16, 256, 0, stream>>>(cnt, NTOT);
  k_embed<<<NTOT, 256, 0, stream>>>(pe, ae, qe, cur, tot);
  k_hist<<<NEDGE/256, 256, 0, stream>>>(adj_row, cnt);
  k_scan<<<1, 64, 0, stream>>>(cnt, rowptr, cursor);
  k_scatter<<<NEDGE/256, 256, 0, stream>>>(adj_row, adj_col, adj_val, cursor, ccol, cval);

  for (int blk = 0; blk < 3; ++blk){
    k_spmm<<<NTOT, 256, 0, stream>>>(rowptr, ccol, cval, cur, tb);
    k_gemm<0,0><<<dim3(768/64, NTOT/64), 256, 0, stream>>>(tb, Wqkv, nullptr, qkvb, NTOT, DIM, 768);
    k_attn<<<dim3(NTOT/64, NH), 256, 0, stream>>>(qkvb, ob);
    k_gemm<0,0><<<dim3(DIM/64, NTOT/64), 256, 0, stream>>>(ob, Wo, nullptr, pb, NTOT, DIM, DIM);
    k_add_ln<<<NTOT, 256, 0, stream>>>(tb, pb, g1, be1, ob);          // x1 -> ob
    k_gemm<1,1><<<dim3(FFD/64, NTOT/64), 256, 0, stream>>>(ob, W1, b1, hb, NTOT, DIM, FFD);   // qkv dead
    k_gemm<0,1><<<dim3(DIM/64, NTOT/64), 256, 0, stream>>>(hb, W2, b2, pb, NTOT, FFD, DIM);
    k_add_ln<<<NTOT, 256, 0, stream>>>(ob, pb, g2, be2, tb);          // x2 -> tb
    k_update<<<NTOT, 256, 0, stream>>>(tb, cur, tot);
  }
  k_out<<<NTOT, 256, 0, stream>>>(tot, out);
}

// Round 7
// 1068.025 us; speedup vs baseline: 1.9490x; 1.9490x over previous
//
#include <hip/hip_runtime.h>
#include <hip/hip_bf16.h>

// ProteinGNNTransformer — round 6 resubmission (round-6 bench died with
// UnresponsiveContainer before compile): attention on MFMA (bf16), rest unchanged.
// qkv GEMM writes bf16 directly (attention is sole consumer).

#define NPROT 3000
#define NAA   25
#define NPROP 1071
#define NTOT  4096
#define DIM   256
#define NH    8
#define DHD   32
#define FFD   1024
#define NEDGE 131072
#define LNEPS 1e-5f

typedef __attribute__((ext_vector_type(8))) short short8v;
typedef __attribute__((ext_vector_type(4))) float float4v;

__device__ __forceinline__ unsigned short f2bu(float x){
  union { __hip_bfloat16 h; unsigned short u; } c; c.h = __float2bfloat16(x); return c.u;
}
__device__ __forceinline__ float4v mfma16(short8v a, short8v b, float4v c){
  return __builtin_amdgcn_mfma_f32_16x16x32_bf16(a, b, c, 0, 0, 0);
}

// ---------------- embedding concat ----------------
__global__ __launch_bounds__(256) void k_embed(const float* __restrict__ pe, const float* __restrict__ ae,
                                               const float* __restrict__ qe,
                                               float* __restrict__ cur, float* __restrict__ tot){
  int i = blockIdx.x*256 + threadIdx.x;
  int row = i >> 8;
  float v;
  if (row < NPROT)           v = pe[i];
  else if (row < NPROT+NAA)  v = ae[i - NPROT*DIM];
  else                       v = qe[i - (NPROT+NAA)*DIM];
  cur[i] = v; tot[i] = v;
}

__global__ __launch_bounds__(256) void k_zero(int* __restrict__ p, int n){
  int i = blockIdx.x*256 + threadIdx.x; if (i < n) p[i] = 0;
}

// ---------------- CSR build ----------------
__global__ __launch_bounds__(256) void k_hist(const int* __restrict__ rows, int* __restrict__ cnt){
  int e = blockIdx.x*256 + threadIdx.x; if (e < NEDGE) atomicAdd(&cnt[rows[e]], 1);
}

__global__ __launch_bounds__(64) void k_scan(const int* __restrict__ cnt, int* __restrict__ rowptr,
                                             int* __restrict__ cursor){
  int lane = threadIdx.x;
  int sum = 0;
  for (int i = 0; i < 64; ++i) sum += cnt[lane*64 + i];
  int pref = sum;
  #pragma unroll
  for (int off = 1; off < 64; off <<= 1){
    int u = __shfl_up(pref, off);
    if (lane >= off) pref += u;
  }
  int run = pref - sum;
  for (int i = 0; i < 64; ++i){
    int c = cnt[lane*64 + i];
    rowptr[lane*64 + i] = run;
    cursor[lane*64 + i] = run;
    run += c;
  }
  if (lane == 63) rowptr[NTOT] = run;
}

__global__ __launch_bounds__(256) void k_scatter(const int* __restrict__ rows, const int* __restrict__ cols,
                                                 const float* __restrict__ vals, int* __restrict__ cursor,
                                                 int* __restrict__ ccol, float* __restrict__ cval){
  int e = blockIdx.x*256 + threadIdx.x; if (e >= NEDGE) return;
  int p = atomicAdd(&cursor[rows[e]], 1);
  ccol[p] = cols[e]; cval[p] = vals[e];
}

// ---------------- SpMM ----------------
__global__ __launch_bounds__(256) void k_spmm(const int* __restrict__ rowptr, const int* __restrict__ ccol,
                                              const float* __restrict__ cval, const float* __restrict__ x,
                                              float* __restrict__ out){
  int r = blockIdx.x, c = threadIdx.x;
  int s = rowptr[r], e = rowptr[r+1];
  float acc = 0.f;
  for (int i = s; i < e; ++i)
    acc += cval[i] * x[((size_t)ccol[i] << 8) + c];
  out[((size_t)r << 8) + c] = acc;
}

// ---------------- tiled GEMM (f32 compute); BF16OUT writes ushort bf16 ----------------
template<int RELU, int BIAS, int BF16OUT>
__global__ __launch_bounds__(256) void k_gemm(const float* __restrict__ A, const float* __restrict__ W,
                                              const float* __restrict__ bias, void* __restrict__ Cv,
                                              int M, int K, int Nc){
  __shared__ float As[16][65];
  __shared__ float Ws[16][65];
  const int tid = threadIdx.x;
  const int tx = tid & 15, ty = tid >> 4;
  const int row0 = blockIdx.y * 64, col0 = blockIdx.x * 64;
  float acc[4][4] = {};
  for (int k0 = 0; k0 < K; k0 += 16){
    #pragma unroll
    for (int j = 0; j < 4; ++j){
      int idx = tid*4 + j;
      As[idx & 15][idx >> 4] = A[(size_t)(row0 + (idx >> 4))*K + k0 + (idx & 15)];
    }
    #pragma unroll
    for (int j = 0; j < 4; ++j){
      int idx = tid*4 + j;
      Ws[idx >> 6][idx & 63] = W[(size_t)(k0 + (idx >> 6))*Nc + col0 + (idx & 63)];
    }
    __syncthreads();
    #pragma unroll
    for (int kk = 0; kk < 16; ++kk){
      float a0 = As[kk][ty*4+0], a1 = As[kk][ty*4+1], a2 = As[kk][ty*4+2], a3 = As[kk][ty*4+3];
      float w0 = Ws[kk][tx*4+0], w1 = Ws[kk][tx*4+1], w2 = Ws[kk][tx*4+2], w3 = Ws[kk][tx*4+3];
      acc[0][0]+=a0*w0; acc[0][1]+=a0*w1; acc[0][2]+=a0*w2; acc[0][3]+=a0*w3;
      acc[1][0]+=a1*w0; acc[1][1]+=a1*w1; acc[1][2]+=a1*w2; acc[1][3]+=a1*w3;
      acc[2][0]+=a2*w0; acc[2][1]+=a2*w1; acc[2][2]+=a2*w2; acc[2][3]+=a2*w3;
      acc[3][0]+=a3*w0; acc[3][1]+=a3*w1; acc[3][2]+=a3*w2; acc[3][3]+=a3*w3;
    }
    __syncthreads();
  }
  #pragma unroll
  for (int i = 0; i < 4; ++i){
    #pragma unroll
    for (int j = 0; j < 4; ++j){
      float v = acc[i][j];
      if (BIAS) v += bias[col0 + tx*4 + j];
      if (RELU) v = fmaxf(v, 0.f);
      size_t oi = (size_t)(row0 + ty*4 + i)*Nc + col0 + tx*4 + j;
      if (BF16OUT) ((unsigned short*)Cv)[oi] = f2bu(v);
      else         ((float*)Cv)[oi] = v;
    }
  }
}

// ---------------- MFMA flash attention ----------------
// grid (NTOT/64, NH); 256 thr = 4 waves; wave w owns q rows [qb+16w, qb+16w+16).
// qbf: bf16 qkv [NTOT][768]. o: f32 [NTOT][256].
// Frag maps (mfma_f32_16x16x32_bf16): A[m][k]: m=lane&15, k=8*(lane>>4)+j;
// B[k][n]: n=lane&15, k=8*(lane>>4)+j; D: row=(lane>>4)*4+reg, col=lane&15.
__global__ __launch_bounds__(256) void k_attn_mfma(const unsigned short* __restrict__ qbf,
                                                   float* __restrict__ o){
  __shared__ unsigned short Kl[64*32];       // [kv][dh] linear
  __shared__ unsigned short Vt[32*64];       // [dh][kv], slot-swizzled (^ row&7)
  __shared__ unsigned short Pl[4][16*64];    // per-wave [q][kv], slot-swizzled
  const int h   = blockIdx.y;
  const int qb  = blockIdx.x * 64;
  const int tid = threadIdx.x;
  const int w   = tid >> 6;
  const int l   = tid & 63;
  const int lr  = l & 15;
  const int g   = l >> 4;
  const int sr  = tid >> 2;                  // staging kv-row 0..63
  const int sq  = tid & 3;                   // staging dh-octet
  const float SC = 0.17677669529663687f;     // 1/sqrt(32)

  // Q fragment: rows qb+16w+lr, dh 8g..8g+7
  short8v qf = *(const short8v*)(qbf + (size_t)(qb + 16*w + lr)*768 + h*DHD + 8*g);

  float4v oa0 = {0.f,0.f,0.f,0.f}, oa1 = {0.f,0.f,0.f,0.f};
  float mrun[4] = {-1e30f,-1e30f,-1e30f,-1e30f};
  float lrun[4] = {0.f,0.f,0.f,0.f};
  unsigned short* pw = &Pl[w][0];

  for (int k0 = 0; k0 < NTOT; k0 += 64){
    // ---- stage K tile (linear) and V tile (transposed+swizzled) ----
    *(short8v*)(Kl + sr*32 + 8*sq) =
        *(const short8v*)(qbf + (size_t)(k0+sr)*768 + 256 + h*DHD + 8*sq);
    short8v vv = *(const short8v*)(qbf + (size_t)(k0+sr)*768 + 512 + h*DHD + 8*sq);
    #pragma unroll
    for (int j = 0; j < 8; ++j){
      int row  = 8*sq + j;                       // dh
      int slot = (sr >> 3) ^ j;                  // (row&7)==j
      Vt[row*64 + slot*8 + (sr & 7)] = (unsigned short)vv[j];
    }
    __syncthreads();

    // ---- S = Q K^T (4 n-tiles of 16 kv) ----
    float4v s[4];
    #pragma unroll
    for (int nt = 0; nt < 4; ++nt){
      short8v kf = *(const short8v*)(Kl + (lr + 16*nt)*32 + 8*g);
      s[nt] = mfma16(qf, kf, (float4v){0.f,0.f,0.f,0.f});
    }
    // ---- online softmax (rows 4g+j, cols lr+16nt) ----
    float tm[4], fac[4], rs[4];
    #pragma unroll
    for (int j = 0; j < 4; ++j){
      float a = s[0][j]*SC, b = s[1][j]*SC, c = s[2][j]*SC, d = s[3][j]*SC;
      s[0][j]=a; s[1][j]=b; s[2][j]=c; s[3][j]=d;
      tm[j] = fmaxf(fmaxf(a,b), fmaxf(c,d));
    }
    #pragma unroll
    for (int mask = 1; mask < 16; mask <<= 1){
      #pragma unroll
      for (int j = 0; j < 4; ++j) tm[j] = fmaxf(tm[j], __shfl_xor(tm[j], mask));
    }
    #pragma unroll
    for (int j = 0; j < 4; ++j){
      float mn = fmaxf(mrun[j], tm[j]);
      fac[j] = __expf(mrun[j] - mn);
      mrun[j] = mn;
      rs[j] = 0.f;
    }
    #pragma unroll
    for (int nt = 0; nt < 4; ++nt){
      #pragma unroll
      for (int j = 0; j < 4; ++j){
        float p = __expf(s[nt][j] - mrun[j]);
        s[nt][j] = p;
        rs[j] += p;
      }
    }
    #pragma unroll
    for (int mask = 1; mask < 16; mask <<= 1){
      #pragma unroll
      for (int j = 0; j < 4; ++j) rs[j] += __shfl_xor(rs[j], mask);
    }
    #pragma unroll
    for (int j = 0; j < 4; ++j){
      lrun[j] = lrun[j]*fac[j] + rs[j];
      oa0[j] *= fac[j];
      oa1[j] *= fac[j];
    }
    // ---- P -> LDS (bf16, swizzled) ----
    #pragma unroll
    for (int nt = 0; nt < 4; ++nt){
      #pragma unroll
      for (int j = 0; j < 4; ++j){
        int row  = 4*g + j;
        int c    = lr + 16*nt;
        int slot = (c >> 3) ^ (row & 7);
        pw[row*64 + slot*8 + (c & 7)] = f2bu(s[nt][j]);
      }
    }
    // ---- O += P V (2 kk-steps of 32 kv, 2 dh-tiles) ----
    #pragma unroll
    for (int kk = 0; kk < 2; ++kk){
      int slotp = (4*kk + g) ^ (lr & 7);
      short8v pa = *(const short8v*)(pw + lr*64 + slotp*8);
      short8v v0 = *(const short8v*)(Vt + lr*64        + slotp*8);
      short8v v1 = *(const short8v*)(Vt + (lr+16)*64   + slotp*8);
      oa0 = mfma16(pa, v0, oa0);
      oa1 = mfma16(pa, v1, oa1);
    }
    __syncthreads();
  }

  // ---- epilogue ----
  #pragma unroll
  for (int j = 0; j < 4; ++j){
    float inv = 1.f / lrun[j];
    size_t row = (size_t)(qb + 16*w + 4*g + j);
    o[row*DIM + h*DHD + lr]      = oa0[j]*inv;
    o[row*DIM + h*DHD + 16 + lr] = oa1[j]*inv;
  }
}

// ---------------- fused residual + LayerNorm ----------------
__global__ __launch_bounds__(256) void k_add_ln(const float* __restrict__ a, const float* __restrict__ b,
                                                const float* __restrict__ g, const float* __restrict__ be,
                                                float* __restrict__ out){
  __shared__ float red[4];
  int r = blockIdx.x, c = threadIdx.x;
  float v = a[((size_t)r << 8) + c] + b[((size_t)r << 8) + c];
  float s = v;
  #pragma unroll
  for (int off = 32; off; off >>= 1) s += __shfl_down(s, off);
  if ((c & 63) == 0) red[c >> 6] = s;
  __syncthreads();
  float mean = (red[0]+red[1]+red[2]+red[3]) * (1.f/DIM);
  __syncthreads();
  float d = v - mean;
  float s2 = d*d;
  #pragma unroll
  for (int off = 32; off; off >>= 1) s2 += __shfl_down(s2, off);
  if ((c & 63) == 0) red[c >> 6] = s2;
  __syncthreads();
  float var = (red[0]+red[1]+red[2]+red[3]) * (1.f/DIM);
  out[((size_t)r << 8) + c] = d * rsqrtf(var + LNEPS) * g[c] + be[c];
}

// ---------------- cur += x2; total += cur ----------------
__global__ __launch_bounds__(256) void k_update(const float* __restrict__ x2, float* __restrict__ cur,
                                                float* __restrict__ tot){
  int i = blockIdx.x*256 + threadIdx.x;
  float c = cur[i] + x2[i];
  cur[i] = c;
  tot[i] += c;
}

// ---------------- output ----------------
__global__ __launch_bounds__(256) void k_out(const float* __restrict__ tot, float* __restrict__ out){
  int i = blockIdx.x*256 + threadIdx.x;
  float v = tot[i];
  out[i] = v;
  out[NTOT*DIM + i] = v;
}

extern "C" void kernel_launch(void* const* d_in, const int* in_sizes, int n_in,
                              void* d_out, int out_size, void* d_ws, size_t ws_size,
                              hipStream_t stream){
  const int*   adj_row = (const int*)  d_in[0];
  const int*   adj_col = (const int*)  d_in[1];
  const float* adj_val = (const float*)d_in[2];
  const float* pe   = (const float*)d_in[3];
  const float* ae   = (const float*)d_in[4];
  const float* qe   = (const float*)d_in[5];
  const float* Wqkv = (const float*)d_in[6];
  const float* Wo   = (const float*)d_in[7];
  const float* W1   = (const float*)d_in[8];
  const float* b1   = (const float*)d_in[9];
  const float* W2   = (const float*)d_in[10];
  const float* b2   = (const float*)d_in[11];
  const float* g1   = (const float*)d_in[12];
  const float* be1  = (const float*)d_in[13];
  const float* g2   = (const float*)d_in[14];
  const float* be2  = (const float*)d_in[15];
  float* out = (float*)d_out;

  // workspace ~37 MB; qbf (bf16 qkv, 6 MB) aliases the FFN-hidden union
  char* w = (char*)d_ws;
  float* cur  = (float*)w; w += (size_t)NTOT*DIM*4;       // 4 MB
  float* tot  = (float*)w; w += (size_t)NTOT*DIM*4;       // 4 MB
  float* tb   = (float*)w; w += (size_t)NTOT*DIM*4;       // 4 MB
  float* ob   = (float*)w; w += (size_t)NTOT*DIM*4;       // 4 MB
  float* pb   = (float*)w; w += (size_t)NTOT*DIM*4;       // 4 MB
  unsigned short* qbf = (unsigned short*)w;                // 6 MB (alias, attn phase)
  float* hb   = (float*)w; w += (size_t)NTOT*FFD*4;       // 16 MB (FFN phase)
  int* rowptr = (int*)w;   w += (size_t)(NTOT+1)*4;
  int* cnt    = (int*)w;   w += (size_t)NTOT*4;
  int* cursor = (int*)w;   w += (size_t)NTOT*4;
  int* ccol   = (int*)w;   w += (size_t)NEDGE*4;
  float* cval = (float*)w; w += (size_t)NEDGE*4;

  k_zero<<<16, 256, 0, stream>>>(cnt, NTOT);
  k_embed<<<NTOT, 256, 0, stream>>>(pe, ae, qe, cur, tot);
  k_hist<<<NEDGE/256, 256, 0, stream>>>(adj_row, cnt);
  k_scan<<<1, 64, 0, stream>>>(cnt, rowptr, cursor);
  k_scatter<<<NEDGE/256, 256, 0, stream>>>(adj_row, adj_col, adj_val, cursor, ccol, cval);

  for (int blk = 0; blk < 3; ++blk){
    k_spmm<<<NTOT, 256, 0, stream>>>(rowptr, ccol, cval, cur, tb);
    k_gemm<0,0,1><<<dim3(768/64, NTOT/64), 256, 0, stream>>>(tb, Wqkv, nullptr, qbf, NTOT, DIM, 768);
    k_attn_mfma<<<dim3(NTOT/64, NH), 256, 0, stream>>>(qbf, ob);
    k_gemm<0,0,0><<<dim3(DIM/64, NTOT/64), 256, 0, stream>>>(ob, Wo, nullptr, pb, NTOT, DIM, DIM);
    k_add_ln<<<NTOT, 256, 0, stream>>>(tb, pb, g1, be1, ob);
    k_gemm<1,1,0><<<dim3(FFD/64, NTOT/64), 256, 0, stream>>>(ob, W1, b1, hb, NTOT, DIM, FFD);
    k_gemm<0,1,0><<<dim3(DIM/64, NTOT/64), 256, 0, stream>>>(hb, W2, b2, pb, NTOT, FFD, DIM);
    k_add_ln<<<NTOT, 256, 0, stream>>>(ob, pb, g2, be2, tb);
    k_update<<<NTOT, 256, 0, stream>>>(tb, cur, tot);
  }
  k_out<<<NTOT, 256, 0, stream>>>(tot, out);
}

// Round 8
// 680.557 us; speedup vs baseline: 3.0586x; 1.5693x over previous
//
#include <hip/hip_runtime.h>
#include <hip/hip_bf16.h>

// ProteinGNNTransformer — round 8: all four GEMMs on bf16 MFMA (f32 accum).
// Weights transposed+converted to bf16 once per launch; activations carry
// bf16 shadows where a GEMM consumes them. Attention unchanged (bf16 out now).

#define NPROT 3000
#define NAA   25
#define NPROP 1071
#define NTOT  4096
#define DIM   256
#define NH    8
#define DHD   32
#define FFD   1024
#define NEDGE 131072
#define LNEPS 1e-5f

typedef unsigned short u16;
typedef __attribute__((ext_vector_type(8))) short short8v;
typedef __attribute__((ext_vector_type(4))) float float4v;

__device__ __forceinline__ u16 f2bu(float x){
  union { __hip_bfloat16 h; u16 u; } c; c.h = __float2bfloat16(x); return c.u;
}
__device__ __forceinline__ float4v mfma16(short8v a, short8v b, float4v c){
  return __builtin_amdgcn_mfma_f32_16x16x32_bf16(a, b, c, 0, 0, 0);
}

// ---------------- embedding concat ----------------
__global__ __launch_bounds__(256) void k_embed(const float* __restrict__ pe, const float* __restrict__ ae,
                                               const float* __restrict__ qe,
                                               float* __restrict__ cur, float* __restrict__ tot){
  int i = blockIdx.x*256 + threadIdx.x;
  int row = i >> 8;
  float v;
  if (row < NPROT)           v = pe[i];
  else if (row < NPROT+NAA)  v = ae[i - NPROT*DIM];
  else                       v = qe[i - (NPROT+NAA)*DIM];
  cur[i] = v; tot[i] = v;
}

__global__ __launch_bounds__(256) void k_zero(int* __restrict__ p, int n){
  int i = blockIdx.x*256 + threadIdx.x; if (i < n) p[i] = 0;
}

// ---------------- weight transpose+convert: Wt[n][k] = bf16(W[k][n]) ----------------
__global__ __launch_bounds__(256) void k_wconv(const float* __restrict__ W, u16* __restrict__ Wt,
                                               int K, int N){
  int n = blockIdx.x;
  for (int k = threadIdx.x; k < K; k += 256)
    Wt[(size_t)n*K + k] = f2bu(W[(size_t)k*N + n]);
}

// ---------------- CSR build ----------------
__global__ __launch_bounds__(256) void k_hist(const int* __restrict__ rows, int* __restrict__ cnt){
  int e = blockIdx.x*256 + threadIdx.x; if (e < NEDGE) atomicAdd(&cnt[rows[e]], 1);
}

__global__ __launch_bounds__(64) void k_scan(const int* __restrict__ cnt, int* __restrict__ rowptr,
                                             int* __restrict__ cursor){
  int lane = threadIdx.x;
  int sum = 0;
  for (int i = 0; i < 64; ++i) sum += cnt[lane*64 + i];
  int pref = sum;
  #pragma unroll
  for (int off = 1; off < 64; off <<= 1){
    int u = __shfl_up(pref, off);
    if (lane >= off) pref += u;
  }
  int run = pref - sum;
  for (int i = 0; i < 64; ++i){
    int c = cnt[lane*64 + i];
    rowptr[lane*64 + i] = run;
    cursor[lane*64 + i] = run;
    run += c;
  }
  if (lane == 63) rowptr[NTOT] = run;
}

__global__ __launch_bounds__(256) void k_scatter(const int* __restrict__ rows, const int* __restrict__ cols,
                                                 const float* __restrict__ vals, int* __restrict__ cursor,
                                                 int* __restrict__ ccol, float* __restrict__ cval){
  int e = blockIdx.x*256 + threadIdx.x; if (e >= NEDGE) return;
  int p = atomicAdd(&cursor[rows[e]], 1);
  ccol[p] = cols[e]; cval[p] = vals[e];
}

// ---------------- SpMM: f32 out + bf16 shadow ----------------
__global__ __launch_bounds__(256) void k_spmm(const int* __restrict__ rowptr, const int* __restrict__ ccol,
                                              const float* __restrict__ cval, const float* __restrict__ x,
                                              float* __restrict__ out, u16* __restrict__ outb){
  int r = blockIdx.x, c = threadIdx.x;
  int s = rowptr[r], e = rowptr[r+1];
  float acc = 0.f;
  for (int i = s; i < e; ++i)
    acc += cval[i] * x[((size_t)ccol[i] << 8) + c];
  out[((size_t)r << 8) + c] = acc;
  outb[((size_t)r << 8) + c] = f2bu(acc);
}

// ---------------- MFMA GEMM: C[M,Nc] = A(bf16[M][K]) @ Wt(bf16[Nc][K])^T ----------------
// 128x128 tile, BK=64, 4 waves 2x2 (64x64 each, 4x4 frags of 16x16x32).
// LDS rows 128B with XOR swizzle slot = octet ^ (row&7)  (guide §6 G4).
template<int RELU, int BIAS, int BF16OUT>
__global__ __launch_bounds__(256) void k_gemm_mfma(const u16* __restrict__ A, const u16* __restrict__ Wt,
                                                   const float* __restrict__ bias, void* __restrict__ Cv,
                                                   int M, int K, int Nc){
  __shared__ u16 Al[128*64];   // 16 KB
  __shared__ u16 Bl[128*64];   // 16 KB
  const int tid = threadIdx.x;
  const int w  = tid >> 6, l = tid & 63, lr = l & 15, g = l >> 4;
  const int row0 = blockIdx.y*128, col0 = blockIdx.x*128;
  const int wm = (w >> 1)*64, wn = (w & 1)*64;
  const int sm = tid >> 1;               // staging row 0..127
  const int so = (tid & 1)*4;            // first octet (0 or 4)
  float4v acc[4][4] = {};

  for (int k0 = 0; k0 < K; k0 += 64){
    const u16* As = A  + (size_t)(row0 + sm)*K + k0 + so*8;
    const u16* Bs = Wt + (size_t)(col0 + sm)*K + k0 + so*8;
    #pragma unroll
    for (int j = 0; j < 4; ++j){
      int o = so + j;
      int slot = o ^ (sm & 7);
      *(short8v*)(Al + sm*64 + slot*8) = *(const short8v*)(As + j*8);
      *(short8v*)(Bl + sm*64 + slot*8) = *(const short8v*)(Bs + j*8);
    }
    __syncthreads();
    #pragma unroll
    for (int kk = 0; kk < 2; ++kk){
      short8v af[4], bfr[4];
      #pragma unroll
      for (int i = 0; i < 4; ++i){
        int am = wm + 16*i + lr;
        af[i]  = *(const short8v*)(Al + am*64 + (((4*kk + g) ^ (am & 7))*8));
        int bn = wn + 16*i + lr;
        bfr[i] = *(const short8v*)(Bl + bn*64 + (((4*kk + g) ^ (bn & 7))*8));
      }
      #pragma unroll
      for (int mi = 0; mi < 4; ++mi)
        #pragma unroll
        for (int ni = 0; ni < 4; ++ni)
          acc[mi][ni] = mfma16(af[mi], bfr[ni], acc[mi][ni]);
    }
    __syncthreads();
  }

  #pragma unroll
  for (int mi = 0; mi < 4; ++mi){
    #pragma unroll
    for (int ni = 0; ni < 4; ++ni){
      int col = col0 + wn + 16*ni + lr;
      float bv = BIAS ? bias[col] : 0.f;
      #pragma unroll
      for (int j = 0; j < 4; ++j){
        int row = row0 + wm + 16*mi + 4*g + j;
        float v = acc[mi][ni][j] + bv;
        if (RELU) v = fmaxf(v, 0.f);
        if (BF16OUT) ((u16*)Cv)[(size_t)row*Nc + col] = f2bu(v);
        else         ((float*)Cv)[(size_t)row*Nc + col] = v;
      }
    }
  }
}

// ---------------- MFMA flash attention (as round 7; bf16 output) ----------------
__global__ __launch_bounds__(256) void k_attn_mfma(const u16* __restrict__ qbf,
                                                   u16* __restrict__ o){
  __shared__ u16 Kl[64*32];
  __shared__ u16 Vt[32*64];
  __shared__ u16 Pl[4][16*64];
  const int h   = blockIdx.y;
  const int qb  = blockIdx.x * 64;
  const int tid = threadIdx.x;
  const int w   = tid >> 6;
  const int l   = tid & 63;
  const int lr  = l & 15;
  const int g   = l >> 4;
  const int sr  = tid >> 2;
  const int sq  = tid & 3;
  const float SC = 0.17677669529663687f;

  short8v qf = *(const short8v*)(qbf + (size_t)(qb + 16*w + lr)*768 + h*DHD + 8*g);

  float4v oa0 = {0.f,0.f,0.f,0.f}, oa1 = {0.f,0.f,0.f,0.f};
  float mrun[4] = {-1e30f,-1e30f,-1e30f,-1e30f};
  float lrun[4] = {0.f,0.f,0.f,0.f};
  u16* pw = &Pl[w][0];

  for (int k0 = 0; k0 < NTOT; k0 += 64){
    *(short8v*)(Kl + sr*32 + 8*sq) =
        *(const short8v*)(qbf + (size_t)(k0+sr)*768 + 256 + h*DHD + 8*sq);
    short8v vv = *(const short8v*)(qbf + (size_t)(k0+sr)*768 + 512 + h*DHD + 8*sq);
    #pragma unroll
    for (int j = 0; j < 8; ++j){
      int row  = 8*sq + j;
      int slot = (sr >> 3) ^ j;
      Vt[row*64 + slot*8 + (sr & 7)] = (u16)vv[j];
    }
    __syncthreads();

    float4v s[4];
    #pragma unroll
    for (int nt = 0; nt < 4; ++nt){
      short8v kf = *(const short8v*)(Kl + (lr + 16*nt)*32 + 8*g);
      s[nt] = mfma16(qf, kf, (float4v){0.f,0.f,0.f,0.f});
    }
    float tm[4], fac[4], rs[4];
    #pragma unroll
    for (int j = 0; j < 4; ++j){
      float a = s[0][j]*SC, b = s[1][j]*SC, c = s[2][j]*SC, d = s[3][j]*SC;
      s[0][j]=a; s[1][j]=b; s[2][j]=c; s[3][j]=d;
      tm[j] = fmaxf(fmaxf(a,b), fmaxf(c,d));
    }
    #pragma unroll
    for (int mask = 1; mask < 16; mask <<= 1){
      #pragma unroll
      for (int j = 0; j < 4; ++j) tm[j] = fmaxf(tm[j], __shfl_xor(tm[j], mask));
    }
    #pragma unroll
    for (int j = 0; j < 4; ++j){
      float mn = fmaxf(mrun[j], tm[j]);
      fac[j] = __expf(mrun[j] - mn);
      mrun[j] = mn;
      rs[j] = 0.f;
    }
    #pragma unroll
    for (int nt = 0; nt < 4; ++nt){
      #pragma unroll
      for (int j = 0; j < 4; ++j){
        float p = __expf(s[nt][j] - mrun[j]);
        s[nt][j] = p;
        rs[j] += p;
      }
    }
    #pragma unroll
    for (int mask = 1; mask < 16; mask <<= 1){
      #pragma unroll
      for (int j = 0; j < 4; ++j) rs[j] += __shfl_xor(rs[j], mask);
    }
    #pragma unroll
    for (int j = 0; j < 4; ++j){
      lrun[j] = lrun[j]*fac[j] + rs[j];
      oa0[j] *= fac[j];
      oa1[j] *= fac[j];
    }
    #pragma unroll
    for (int nt = 0; nt < 4; ++nt){
      #pragma unroll
      for (int j = 0; j < 4; ++j){
        int row  = 4*g + j;
        int c    = lr + 16*nt;
        int slot = (c >> 3) ^ (row & 7);
        pw[row*64 + slot*8 + (c & 7)] = f2bu(s[nt][j]);
      }
    }
    #pragma unroll
    for (int kk = 0; kk < 2; ++kk){
      int slotp = (4*kk + g) ^ (lr & 7);
      short8v pa = *(const short8v*)(pw + lr*64 + slotp*8);
      short8v v0 = *(const short8v*)(Vt + lr*64        + slotp*8);
      short8v v1 = *(const short8v*)(Vt + (lr+16)*64   + slotp*8);
      oa0 = mfma16(pa, v0, oa0);
      oa1 = mfma16(pa, v1, oa1);
    }
    __syncthreads();
  }

  #pragma unroll
  for (int j = 0; j < 4; ++j){
    float inv = 1.f / lrun[j];
    size_t row = (size_t)(qb + 16*w + 4*g + j);
    o[row*DIM + h*DHD + lr]      = f2bu(oa0[j]*inv);
    o[row*DIM + h*DHD + 16 + lr] = f2bu(oa1[j]*inv);
  }
}

// ---------------- fused residual + LayerNorm (optional bf16 shadow out) ----------------
template<int DUAL>
__global__ __launch_bounds__(256) void k_add_ln(const float* __restrict__ a, const float* __restrict__ b,
                                                const float* __restrict__ g, const float* __restrict__ be,
                                                float* __restrict__ out, u16* __restrict__ out2){
  __shared__ float red[4];
  int r = blockIdx.x, c = threadIdx.x;
  float v = a[((size_t)r << 8) + c] + b[((size_t)r << 8) + c];
  float s = v;
  #pragma unroll
  for (int off = 32; off; off >>= 1) s += __shfl_down(s, off);
  if ((c & 63) == 0) red[c >> 6] = s;
  __syncthreads();
  float mean = (red[0]+red[1]+red[2]+red[3]) * (1.f/DIM);
  __syncthreads();
  float d = v - mean;
  float s2 = d*d;
  #pragma unroll
  for (int off = 32; off; off >>= 1) s2 += __shfl_down(s2, off);
  if ((c & 63) == 0) red[c >> 6] = s2;
  __syncthreads();
  float var = (red[0]+red[1]+red[2]+red[3]) * (1.f/DIM);
  float rv = d * rsqrtf(var + LNEPS) * g[c] + be[c];
  out[((size_t)r << 8) + c] = rv;
  if (DUAL) out2[((size_t)r << 8) + c] = f2bu(rv);
}

// ---------------- cur += x2; total += cur ----------------
__global__ __launch_bounds__(256) void k_update(const float* __restrict__ x2, float* __restrict__ cur,
                                                float* __restrict__ tot){
  int i = blockIdx.x*256 + threadIdx.x;
  float c = cur[i] + x2[i];
  cur[i] = c;
  tot[i] += c;
}

// ---------------- output ----------------
__global__ __launch_bounds__(256) void k_out(const float* __restrict__ tot, float* __restrict__ out){
  int i = blockIdx.x*256 + threadIdx.x;
  float v = tot[i];
  out[i] = v;
  out[NTOT*DIM + i] = v;
}

extern "C" void kernel_launch(void* const* d_in, const int* in_sizes, int n_in,
                              void* d_out, int out_size, void* d_ws, size_t ws_size,
                              hipStream_t stream){
  const int*   adj_row = (const int*)  d_in[0];
  const int*   adj_col = (const int*)  d_in[1];
  const float* adj_val = (const float*)d_in[2];
  const float* pe   = (const float*)d_in[3];
  const float* ae   = (const float*)d_in[4];
  const float* qe   = (const float*)d_in[5];
  const float* Wqkv = (const float*)d_in[6];
  const float* Wo   = (const float*)d_in[7];
  const float* W1   = (const float*)d_in[8];
  const float* b1   = (const float*)d_in[9];
  const float* W2   = (const float*)d_in[10];
  const float* b2   = (const float*)d_in[11];
  const float* g1   = (const float*)d_in[12];
  const float* be1  = (const float*)d_in[13];
  const float* g2   = (const float*)d_in[14];
  const float* be2  = (const float*)d_in[15];
  float* out = (float*)d_out;

  // ---- workspace (~36.7 MB) ----
  char* w = (char*)d_ws;
  float* cur  = (float*)w; w += (size_t)NTOT*DIM*4;        // 4 MB
  float* tot  = (float*)w; w += (size_t)NTOT*DIM*4;        // 4 MB
  float* tf   = (float*)w; w += (size_t)NTOT*DIM*4;        // 4 MB  (spmm t / x2)
  float* pbuf = (float*)w; w += (size_t)NTOT*DIM*4;        // 4 MB  (proj / ffn2 out)
  float* x1   = (float*)w; w += (size_t)NTOT*DIM*4;        // 4 MB
  u16* tbf    = (u16*)w;   w += (size_t)NTOT*DIM*2;        // 2 MB  (spmm bf16)
  u16* obf    = (u16*)w;   w += (size_t)NTOT*DIM*2;        // 2 MB  (attn out bf16)
  u16* x1b    = (u16*)w;   w += (size_t)NTOT*DIM*2;        // 2 MB  (x1 bf16)
  u16* hq     = (u16*)w;   w += (size_t)NTOT*FFD*2;        // 8 MB  (qbf 6MB ∪ h 8MB)
  u16* wqkvt  = (u16*)w;   w += (size_t)768*256*2;
  u16* wot    = (u16*)w;   w += (size_t)256*256*2;
  u16* w1t    = (u16*)w;   w += (size_t)1024*256*2;
  u16* w2t    = (u16*)w;   w += (size_t)256*1024*2;
  int* rowptr = (int*)w;   w += (size_t)(NTOT+1)*4;
  int* cnt    = (int*)w;   w += (size_t)NTOT*4;
  int* cursor = (int*)w;   w += (size_t)NTOT*4;
  int* ccol   = (int*)w;   w += (size_t)NEDGE*4;
  float* cval = (float*)w; w += (size_t)NEDGE*4;
  u16* qbf = hq;                                            // alias

  // ---- one-time per launch: CSR build + weight convert ----
  k_zero<<<16, 256, 0, stream>>>(cnt, NTOT);
  k_embed<<<NTOT, 256, 0, stream>>>(pe, ae, qe, cur, tot);
  k_hist<<<NEDGE/256, 256, 0, stream>>>(adj_row, cnt);
  k_scan<<<1, 64, 0, stream>>>(cnt, rowptr, cursor);
  k_scatter<<<NEDGE/256, 256, 0, stream>>>(adj_row, adj_col, adj_val, cursor, ccol, cval);
  k_wconv<<<768,  256, 0, stream>>>(Wqkv, wqkvt, 256, 768);
  k_wconv<<<256,  256, 0, stream>>>(Wo,   wot,   256, 256);
  k_wconv<<<1024, 256, 0, stream>>>(W1,   w1t,   256, 1024);
  k_wconv<<<256,  256, 0, stream>>>(W2,   w2t,  1024, 256);

  for (int blk = 0; blk < 3; ++blk){
    k_spmm<<<NTOT, 256, 0, stream>>>(rowptr, ccol, cval, cur, tf, tbf);
    k_gemm_mfma<0,0,1><<<dim3(768/128, NTOT/128), 256, 0, stream>>>(tbf, wqkvt, nullptr, qbf, NTOT, 256, 768);
    k_attn_mfma<<<dim3(NTOT/64, NH), 256, 0, stream>>>(qbf, obf);
    k_gemm_mfma<0,0,0><<<dim3(256/128, NTOT/128), 256, 0, stream>>>(obf, wot, nullptr, pbuf, NTOT, 256, 256);
    k_add_ln<1><<<NTOT, 256, 0, stream>>>(tf, pbuf, g1, be1, x1, x1b);
    k_gemm_mfma<1,1,1><<<dim3(1024/128, NTOT/128), 256, 0, stream>>>(x1b, w1t, b1, hq, NTOT, 256, 1024);
    k_gemm_mfma<0,1,0><<<dim3(256/128, NTOT/128), 256, 0, stream>>>(hq, w2t, b2, pbuf, NTOT, 1024, 256);
    k_add_ln<0><<<NTOT, 256, 0, stream>>>(x1, pbuf, g2, be2, tf, nullptr);
    k_update<<<NTOT, 256, 0, stream>>>(tf, cur, tot);
  }
  k_out<<<NTOT, 256, 0, stream>>>(tot, out);
}

// Round 9
// 650.195 us; speedup vs baseline: 3.2015x; 1.0467x over previous
//
#include <hip/hip_runtime.h>
#include <hip/hip_bf16.h>

// ProteinGNNTransformer — round 9: attention split-K ×2 (occupancy 8→16 waves/CU)
// + pipelined global→reg K/V staging. GEMMs/spmm/LN unchanged from round 8.

#define NPROT 3000
#define NAA   25
#define NPROP 1071
#define NTOT  4096
#define DIM   256
#define NH    8
#define DHD   32
#define FFD   1024
#define NEDGE 131072
#define LNEPS 1e-5f
#define KSPLIT 2
#define KVHALF (NTOT/KSPLIT)

typedef unsigned short u16;
typedef __attribute__((ext_vector_type(8))) short short8v;
typedef __attribute__((ext_vector_type(4))) float float4v;

__device__ __forceinline__ u16 f2bu(float x){
  union { __hip_bfloat16 h; u16 u; } c; c.h = __float2bfloat16(x); return c.u;
}
__device__ __forceinline__ float4v mfma16(short8v a, short8v b, float4v c){
  return __builtin_amdgcn_mfma_f32_16x16x32_bf16(a, b, c, 0, 0, 0);
}

// ---------------- embedding concat ----------------
__global__ __launch_bounds__(256) void k_embed(const float* __restrict__ pe, const float* __restrict__ ae,
                                               const float* __restrict__ qe,
                                               float* __restrict__ cur, float* __restrict__ tot){
  int i = blockIdx.x*256 + threadIdx.x;
  int row = i >> 8;
  float v;
  if (row < NPROT)           v = pe[i];
  else if (row < NPROT+NAA)  v = ae[i - NPROT*DIM];
  else                       v = qe[i - (NPROT+NAA)*DIM];
  cur[i] = v; tot[i] = v;
}

__global__ __launch_bounds__(256) void k_zero(int* __restrict__ p, int n){
  int i = blockIdx.x*256 + threadIdx.x; if (i < n) p[i] = 0;
}

// ---------------- weight transpose+convert ----------------
__global__ __launch_bounds__(256) void k_wconv(const float* __restrict__ W, u16* __restrict__ Wt,
                                               int K, int N){
  int n = blockIdx.x;
  for (int k = threadIdx.x; k < K; k += 256)
    Wt[(size_t)n*K + k] = f2bu(W[(size_t)k*N + n]);
}

// ---------------- CSR build ----------------
__global__ __launch_bounds__(256) void k_hist(const int* __restrict__ rows, int* __restrict__ cnt){
  int e = blockIdx.x*256 + threadIdx.x; if (e < NEDGE) atomicAdd(&cnt[rows[e]], 1);
}

__global__ __launch_bounds__(64) void k_scan(const int* __restrict__ cnt, int* __restrict__ rowptr,
                                             int* __restrict__ cursor){
  int lane = threadIdx.x;
  int sum = 0;
  for (int i = 0; i < 64; ++i) sum += cnt[lane*64 + i];
  int pref = sum;
  #pragma unroll
  for (int off = 1; off < 64; off <<= 1){
    int u = __shfl_up(pref, off);
    if (lane >= off) pref += u;
  }
  int run = pref - sum;
  for (int i = 0; i < 64; ++i){
    int c = cnt[lane*64 + i];
    rowptr[lane*64 + i] = run;
    cursor[lane*64 + i] = run;
    run += c;
  }
  if (lane == 63) rowptr[NTOT] = run;
}

__global__ __launch_bounds__(256) void k_scatter(const int* __restrict__ rows, const int* __restrict__ cols,
                                                 const float* __restrict__ vals, int* __restrict__ cursor,
                                                 int* __restrict__ ccol, float* __restrict__ cval){
  int e = blockIdx.x*256 + threadIdx.x; if (e >= NEDGE) return;
  int p = atomicAdd(&cursor[rows[e]], 1);
  ccol[p] = cols[e]; cval[p] = vals[e];
}

// ---------------- SpMM: f32 out + bf16 shadow ----------------
__global__ __launch_bounds__(256) void k_spmm(const int* __restrict__ rowptr, const int* __restrict__ ccol,
                                              const float* __restrict__ cval, const float* __restrict__ x,
                                              float* __restrict__ out, u16* __restrict__ outb){
  int r = blockIdx.x, c = threadIdx.x;
  int s = rowptr[r], e = rowptr[r+1];
  float acc = 0.f;
  for (int i = s; i < e; ++i)
    acc += cval[i] * x[((size_t)ccol[i] << 8) + c];
  out[((size_t)r << 8) + c] = acc;
  outb[((size_t)r << 8) + c] = f2bu(acc);
}

// ---------------- MFMA GEMM (unchanged from round 8) ----------------
template<int RELU, int BIAS, int BF16OUT>
__global__ __launch_bounds__(256) void k_gemm_mfma(const u16* __restrict__ A, const u16* __restrict__ Wt,
                                                   const float* __restrict__ bias, void* __restrict__ Cv,
                                                   int M, int K, int Nc){
  __shared__ u16 Al[128*64];
  __shared__ u16 Bl[128*64];
  const int tid = threadIdx.x;
  const int w  = tid >> 6, l = tid & 63, lr = l & 15, g = l >> 4;
  const int row0 = blockIdx.y*128, col0 = blockIdx.x*128;
  const int wm = (w >> 1)*64, wn = (w & 1)*64;
  const int sm = tid >> 1;
  const int so = (tid & 1)*4;
  float4v acc[4][4] = {};

  for (int k0 = 0; k0 < K; k0 += 64){
    const u16* As = A  + (size_t)(row0 + sm)*K + k0 + so*8;
    const u16* Bs = Wt + (size_t)(col0 + sm)*K + k0 + so*8;
    #pragma unroll
    for (int j = 0; j < 4; ++j){
      int o = so + j;
      int slot = o ^ (sm & 7);
      *(short8v*)(Al + sm*64 + slot*8) = *(const short8v*)(As + j*8);
      *(short8v*)(Bl + sm*64 + slot*8) = *(const short8v*)(Bs + j*8);
    }
    __syncthreads();
    #pragma unroll
    for (int kk = 0; kk < 2; ++kk){
      short8v af[4], bfr[4];
      #pragma unroll
      for (int i = 0; i < 4; ++i){
        int am = wm + 16*i + lr;
        af[i]  = *(const short8v*)(Al + am*64 + (((4*kk + g) ^ (am & 7))*8));
        int bn = wn + 16*i + lr;
        bfr[i] = *(const short8v*)(Bl + bn*64 + (((4*kk + g) ^ (bn & 7))*8));
      }
      #pragma unroll
      for (int mi = 0; mi < 4; ++mi)
        #pragma unroll
        for (int ni = 0; ni < 4; ++ni)
          acc[mi][ni] = mfma16(af[mi], bfr[ni], acc[mi][ni]);
    }
    __syncthreads();
  }

  #pragma unroll
  for (int mi = 0; mi < 4; ++mi){
    #pragma unroll
    for (int ni = 0; ni < 4; ++ni){
      int col = col0 + wn + 16*ni + lr;
      float bv = BIAS ? bias[col] : 0.f;
      #pragma unroll
      for (int j = 0; j < 4; ++j){
        int row = row0 + wm + 16*mi + 4*g + j;
        float v = acc[mi][ni][j] + bv;
        if (RELU) v = fmaxf(v, 0.f);
        if (BF16OUT) ((u16*)Cv)[(size_t)row*Nc + col] = f2bu(v);
        else         ((float*)Cv)[(size_t)row*Nc + col] = v;
      }
    }
  }
}

// ---------------- MFMA flash attention, split-K partial ----------------
// grid (NTOT/64, NH, KSPLIT); writes UNNORMALIZED O partial (f32) + scaled (m,l).
__global__ __launch_bounds__(256) void k_attn_mfma(const u16* __restrict__ qbf,
                                                   float* __restrict__ op0, float* __restrict__ op1,
                                                   float* __restrict__ mbuf, float* __restrict__ lbuf){
  __shared__ u16 Kl[64*32];
  __shared__ u16 Vt[32*64];
  __shared__ u16 Pl[4][16*64];
  const int h   = blockIdx.y;
  const int ks  = blockIdx.z;
  const int qb  = blockIdx.x * 64;
  const int tid = threadIdx.x;
  const int w   = tid >> 6;
  const int l   = tid & 63;
  const int lr  = l & 15;
  const int g   = l >> 4;
  const int sr  = tid >> 2;
  const int sq  = tid & 3;
  const float SC = 0.17677669529663687f;

  float* opart = ks ? op1 : op0;

  short8v qf = *(const short8v*)(qbf + (size_t)(qb + 16*w + lr)*768 + h*DHD + 8*g);

  float4v oa0 = {0.f,0.f,0.f,0.f}, oa1 = {0.f,0.f,0.f,0.f};
  float mrun[4] = {-1e30f,-1e30f,-1e30f,-1e30f};   // raw (unscaled) running max
  float lrun[4] = {0.f,0.f,0.f,0.f};
  u16* pw = &Pl[w][0];

  // pipelined staging: regs hold tile t; loads for t+1 issued during compute of t
  const u16* kp = qbf + (size_t)(ks*KVHALF + sr)*768 + 256 + h*DHD + 8*sq;
  const u16* vp = kp + 256;
  short8v kreg = *(const short8v*)kp;
  short8v vreg = *(const short8v*)vp;

  const int NIT = KVHALF/64;
  for (int t = 0; t < NIT; ++t){
    // ---- LDS write of tile t ----
    *(short8v*)(Kl + sr*32 + 8*sq) = kreg;
    #pragma unroll
    for (int j = 0; j < 8; ++j){
      int row  = 8*sq + j;
      int slot = (sr >> 3) ^ j;
      Vt[row*64 + slot*8 + (sr & 7)] = (u16)vreg[j];
    }
    __syncthreads();
    // ---- issue loads for t+1 (latency hidden under compute below) ----
    kp += 64*768; vp += 64*768;
    if (t + 1 < NIT){
      kreg = *(const short8v*)kp;
      vreg = *(const short8v*)vp;
    }

    // ---- S = Q K^T ----
    float4v s[4];
    #pragma unroll
    for (int nt = 0; nt < 4; ++nt){
      short8v kf = *(const short8v*)(Kl + (lr + 16*nt)*32 + 8*g);
      s[nt] = mfma16(qf, kf, (float4v){0.f,0.f,0.f,0.f});
    }
    // ---- online softmax (max in raw domain, scale folded into exp) ----
    float tm[4], fac[4], rs[4];
    #pragma unroll
    for (int j = 0; j < 4; ++j)
      tm[j] = fmaxf(fmaxf(s[0][j], s[1][j]), fmaxf(s[2][j], s[3][j]));
    #pragma unroll
    for (int mask = 1; mask < 16; mask <<= 1){
      #pragma unroll
      for (int j = 0; j < 4; ++j) tm[j] = fmaxf(tm[j], __shfl_xor(tm[j], mask));
    }
    float mns[4];
    #pragma unroll
    for (int j = 0; j < 4; ++j){
      float mn = fmaxf(mrun[j], tm[j]);
      fac[j] = __expf((mrun[j] - mn)*SC);
      mrun[j] = mn;
      mns[j] = mn*SC;
      rs[j] = 0.f;
    }
    #pragma unroll
    for (int nt = 0; nt < 4; ++nt){
      #pragma unroll
      for (int j = 0; j < 4; ++j){
        float p = __expf(__builtin_fmaf(s[nt][j], SC, -mns[j]));
        s[nt][j] = p;
        rs[j] += p;
      }
    }
    #pragma unroll
    for (int mask = 1; mask < 16; mask <<= 1){
      #pragma unroll
      for (int j = 0; j < 4; ++j) rs[j] += __shfl_xor(rs[j], mask);
    }
    #pragma unroll
    for (int j = 0; j < 4; ++j){
      lrun[j] = lrun[j]*fac[j] + rs[j];
      oa0[j] *= fac[j];
      oa1[j] *= fac[j];
    }
    // ---- P -> LDS (bf16, swizzled) ----
    #pragma unroll
    for (int nt = 0; nt < 4; ++nt){
      #pragma unroll
      for (int j = 0; j < 4; ++j){
        int row  = 4*g + j;
        int c    = lr + 16*nt;
        int slot = (c >> 3) ^ (row & 7);
        pw[row*64 + slot*8 + (c & 7)] = f2bu(s[nt][j]);
      }
    }
    // ---- O += P V ----
    #pragma unroll
    for (int kk = 0; kk < 2; ++kk){
      int slotp = (4*kk + g) ^ (lr & 7);
      short8v pa = *(const short8v*)(pw + lr*64 + slotp*8);
      short8v v0 = *(const short8v*)(Vt + lr*64        + slotp*8);
      short8v v1 = *(const short8v*)(Vt + (lr+16)*64   + slotp*8);
      oa0 = mfma16(pa, v0, oa0);
      oa1 = mfma16(pa, v1, oa1);
    }
    __syncthreads();
  }

  // ---- epilogue: unnormalized partial O + scaled (m,l) ----
  #pragma unroll
  for (int j = 0; j < 4; ++j){
    size_t row = (size_t)(qb + 16*w + 4*g + j);
    opart[row*DIM + h*DHD + lr]      = oa0[j];
    opart[row*DIM + h*DHD + 16 + lr] = oa1[j];
    if (lr == 0){
      size_t mi = (size_t)(ks*NH + h)*NTOT + row;
      mbuf[mi] = mrun[j]*SC;      // scaled-domain max
      lbuf[mi] = lrun[j];
    }
  }
}

// ---------------- split-K merge: obf = bf16( (w0 O0 + w1 O1) / (w0 l0 + w1 l1) ) ----------------
__global__ __launch_bounds__(256) void k_attn_merge(const float* __restrict__ o0, const float* __restrict__ o1,
                                                    const float* __restrict__ mbuf, const float* __restrict__ lbuf,
                                                    u16* __restrict__ obf){
  int i = blockIdx.x*256 + threadIdx.x;
  int r = i >> 8, c = i & 255, h = c >> 5;
  size_t i0 = (size_t)h*NTOT + r;
  size_t i1 = (size_t)(NH + h)*NTOT + r;
  float m0 = mbuf[i0], m1 = mbuf[i1];
  float M  = fmaxf(m0, m1);
  float w0 = __expf(m0 - M), w1 = __expf(m1 - M);
  float L  = w0*lbuf[i0] + w1*lbuf[i1];
  obf[i] = f2bu((w0*o0[i] + w1*o1[i]) / L);
}

// ---------------- fused residual + LayerNorm ----------------
template<int DUAL>
__global__ __launch_bounds__(256) void k_add_ln(const float* __restrict__ a, const float* __restrict__ b,
                                                const float* __restrict__ g, const float* __restrict__ be,
                                                float* __restrict__ out, u16* __restrict__ out2){
  __shared__ float red[4];
  int r = blockIdx.x, c = threadIdx.x;
  float v = a[((size_t)r << 8) + c] + b[((size_t)r << 8) + c];
  float s = v;
  #pragma unroll
  for (int off = 32; off; off >>= 1) s += __shfl_down(s, off);
  if ((c & 63) == 0) red[c >> 6] = s;
  __syncthreads();
  float mean = (red[0]+red[1]+red[2]+red[3]) * (1.f/DIM);
  __syncthreads();
  float d = v - mean;
  float s2 = d*d;
  #pragma unroll
  for (int off = 32; off; off >>= 1) s2 += __shfl_down(s2, off);
  if ((c & 63) == 0) red[c >> 6] = s2;
  __syncthreads();
  float var = (red[0]+red[1]+red[2]+red[3]) * (1.f/DIM);
  float rv = d * rsqrtf(var + LNEPS) * g[c] + be[c];
  out[((size_t)r << 8) + c] = rv;
  if (DUAL) out2[((size_t)r << 8) + c] = f2bu(rv);
}

// ---------------- cur += x2; total += cur ----------------
__global__ __launch_bounds__(256) void k_update(const float* __restrict__ x2, float* __restrict__ cur,
                                                float* __restrict__ tot){
  int i = blockIdx.x*256 + threadIdx.x;
  float c = cur[i] + x2[i];
  cur[i] = c;
  tot[i] += c;
}

// ---------------- output ----------------
__global__ __launch_bounds__(256) void k_out(const float* __restrict__ tot, float* __restrict__ out){
  int i = blockIdx.x*256 + threadIdx.x;
  float v = tot[i];
  out[i] = v;
  out[NTOT*DIM + i] = v;
}

extern "C" void kernel_launch(void* const* d_in, const int* in_sizes, int n_in,
                              void* d_out, int out_size, void* d_ws, size_t ws_size,
                              hipStream_t stream){
  const int*   adj_row = (const int*)  d_in[0];
  const int*   adj_col = (const int*)  d_in[1];
  const float* adj_val = (const float*)d_in[2];
  const float* pe   = (const float*)d_in[3];
  const float* ae   = (const float*)d_in[4];
  const float* qe   = (const float*)d_in[5];
  const float* Wqkv = (const float*)d_in[6];
  const float* Wo   = (const float*)d_in[7];
  const float* W1   = (const float*)d_in[8];
  const float* b1   = (const float*)d_in[9];
  const float* W2   = (const float*)d_in[10];
  const float* b2   = (const float*)d_in[11];
  const float* g1   = (const float*)d_in[12];
  const float* be1  = (const float*)d_in[13];
  const float* g2   = (const float*)d_in[14];
  const float* be2  = (const float*)d_in[15];
  float* out = (float*)d_out;

  // ---- workspace (~36.7 MB) ----
  char* w = (char*)d_ws;
  float* cur  = (float*)w; w += (size_t)NTOT*DIM*4;        // 4 MB
  float* tot  = (float*)w; w += (size_t)NTOT*DIM*4;        // 4 MB
  float* tf   = (float*)w; w += (size_t)NTOT*DIM*4;        // 4 MB  (spmm t / x2)
  float* pbuf = (float*)w; w += (size_t)NTOT*DIM*4;        // 4 MB  (proj/ffn2 out; attn partial 0)
  float* x1   = (float*)w; w += (size_t)NTOT*DIM*4;        // 4 MB  (x1; attn partial 1)
  u16* tbf    = (u16*)w;   w += (size_t)NTOT*DIM*2;        // 2 MB  (spmm bf16; attn m/l)
  u16* obf    = (u16*)w;   w += (size_t)NTOT*DIM*2;        // 2 MB  (attn out bf16)
  u16* x1b    = (u16*)w;   w += (size_t)NTOT*DIM*2;        // 2 MB
  u16* hq     = (u16*)w;   w += (size_t)NTOT*FFD*2;        // 8 MB  (qbf ∪ h)
  u16* wqkvt  = (u16*)w;   w += (size_t)768*256*2;
  u16* wot    = (u16*)w;   w += (size_t)256*256*2;
  u16* w1t    = (u16*)w;   w += (size_t)1024*256*2;
  u16* w2t    = (u16*)w;   w += (size_t)256*1024*2;
  int* rowptr = (int*)w;   w += (size_t)(NTOT+1)*4;
  int* cnt    = (int*)w;   w += (size_t)NTOT*4;
  int* cursor = (int*)w;   w += (size_t)NTOT*4;
  int* ccol   = (int*)w;   w += (size_t)NEDGE*4;
  float* cval = (float*)w; w += (size_t)NEDGE*4;
  u16* qbf = hq;                                            // alias
  float* mbuf = (float*)tbf;                                // [KSPLIT][NH][NTOT] f32 (256 KB)
  float* lbuf = mbuf + (size_t)KSPLIT*NH*NTOT;              // 256 KB (both inside dead tbf)

  // ---- one-time per launch: CSR build + weight convert ----
  k_zero<<<16, 256, 0, stream>>>(cnt, NTOT);
  k_embed<<<NTOT, 256, 0, stream>>>(pe, ae, qe, cur, tot);
  k_hist<<<NEDGE/256, 256, 0, stream>>>(adj_row, cnt);
  k_scan<<<1, 64, 0, stream>>>(cnt, rowptr, cursor);
  k_scatter<<<NEDGE/256, 256, 0, stream>>>(adj_row, adj_col, adj_val, cursor, ccol, cval);
  k_wconv<<<768,  256, 0, stream>>>(Wqkv, wqkvt, 256, 768);
  k_wconv<<<256,  256, 0, stream>>>(Wo,   wot,   256, 256);
  k_wconv<<<1024, 256, 0, stream>>>(W1,   w1t,   256, 1024);
  k_wconv<<<256,  256, 0, stream>>>(W2,   w2t,  1024, 256);

  for (int blk = 0; blk < 3; ++blk){
    k_spmm<<<NTOT, 256, 0, stream>>>(rowptr, ccol, cval, cur, tf, tbf);
    k_gemm_mfma<0,0,1><<<dim3(768/128, NTOT/128), 256, 0, stream>>>(tbf, wqkvt, nullptr, qbf, NTOT, 256, 768);
    // (qkv GEMM consumed tbf; m/l buffers may now alias it)
    k_attn_mfma<<<dim3(NTOT/64, NH, KSPLIT), 256, 0, stream>>>(qbf, pbuf, x1, mbuf, lbuf);
    k_attn_merge<<<NTOT*DIM/256, 256, 0, stream>>>(pbuf, x1, mbuf, lbuf, obf);
    k_gemm_mfma<0,0,0><<<dim3(256/128, NTOT/128), 256, 0, stream>>>(obf, wot, nullptr, pbuf, NTOT, 256, 256);
    k_add_ln<1><<<NTOT, 256, 0, stream>>>(tf, pbuf, g1, be1, x1, x1b);
    k_gemm_mfma<1,1,1><<<dim3(1024/128, NTOT/128), 256, 0, stream>>>(x1b, w1t, b1, hq, NTOT, 256, 1024);
    k_gemm_mfma<0,1,0><<<dim3(256/128, NTOT/128), 256, 0, stream>>>(hq, w2t, b2, pbuf, NTOT, 1024, 256);
    k_add_ln<0><<<NTOT, 256, 0, stream>>>(x1, pbuf, g2, be2, tf, nullptr);
    k_update<<<NTOT, 256, 0, stream>>>(tf, cur, tot);
  }
  k_out<<<NTOT, 256, 0, stream>>>(tot, out);
}

// Round 10
// 555.160 us; speedup vs baseline: 3.7495x; 1.1712x over previous
//
#include <hip/hip_runtime.h>
#include <hip/hip_bf16.h>

// ProteinGNNTransformer — round 10: attention rework — swapped QK^T (per-lane
// q-row softmax, scalar stats, packed b64 P-writes), K frags direct from L2,
// double-buffered V (1 barrier/iter). GEMMs/spmm/LN unchanged from round 9.

#define NPROT 3000
#define NAA   25
#define NPROP 1071
#define NTOT  4096
#define DIM   256
#define NH    8
#define DHD   32
#define FFD   1024
#define NEDGE 131072
#define LNEPS 1e-5f
#define KSPLIT 2
#define KVHALF (NTOT/KSPLIT)

typedef unsigned short u16;
typedef __attribute__((ext_vector_type(8))) short short8v;
typedef __attribute__((ext_vector_type(4))) float float4v;
typedef __attribute__((ext_vector_type(2))) unsigned int uint2v;

__device__ __forceinline__ u16 f2bu(float x){
  union { __hip_bfloat16 h; u16 u; } c; c.h = __float2bfloat16(x); return c.u;
}
__device__ __forceinline__ float4v mfma16(short8v a, short8v b, float4v c){
  return __builtin_amdgcn_mfma_f32_16x16x32_bf16(a, b, c, 0, 0, 0);
}

// ---------------- embedding concat ----------------
__global__ __launch_bounds__(256) void k_embed(const float* __restrict__ pe, const float* __restrict__ ae,
                                               const float* __restrict__ qe,
                                               float* __restrict__ cur, float* __restrict__ tot){
  int i = blockIdx.x*256 + threadIdx.x;
  int row = i >> 8;
  float v;
  if (row < NPROT)           v = pe[i];
  else if (row < NPROT+NAA)  v = ae[i - NPROT*DIM];
  else                       v = qe[i - (NPROT+NAA)*DIM];
  cur[i] = v; tot[i] = v;
}

__global__ __launch_bounds__(256) void k_zero(int* __restrict__ p, int n){
  int i = blockIdx.x*256 + threadIdx.x; if (i < n) p[i] = 0;
}

// ---------------- weight transpose+convert ----------------
__global__ __launch_bounds__(256) void k_wconv(const float* __restrict__ W, u16* __restrict__ Wt,
                                               int K, int N){
  int n = blockIdx.x;
  for (int k = threadIdx.x; k < K; k += 256)
    Wt[(size_t)n*K + k] = f2bu(W[(size_t)k*N + n]);
}

// ---------------- CSR build ----------------
__global__ __launch_bounds__(256) void k_hist(const int* __restrict__ rows, int* __restrict__ cnt){
  int e = blockIdx.x*256 + threadIdx.x; if (e < NEDGE) atomicAdd(&cnt[rows[e]], 1);
}

__global__ __launch_bounds__(64) void k_scan(const int* __restrict__ cnt, int* __restrict__ rowptr,
                                             int* __restrict__ cursor){
  int lane = threadIdx.x;
  int sum = 0;
  for (int i = 0; i < 64; ++i) sum += cnt[lane*64 + i];
  int pref = sum;
  #pragma unroll
  for (int off = 1; off < 64; off <<= 1){
    int u = __shfl_up(pref, off);
    if (lane >= off) pref += u;
  }
  int run = pref - sum;
  for (int i = 0; i < 64; ++i){
    int c = cnt[lane*64 + i];
    rowptr[lane*64 + i] = run;
    cursor[lane*64 + i] = run;
    run += c;
  }
  if (lane == 63) rowptr[NTOT] = run;
}

__global__ __launch_bounds__(256) void k_scatter(const int* __restrict__ rows, const int* __restrict__ cols,
                                                 const float* __restrict__ vals, int* __restrict__ cursor,
                                                 int* __restrict__ ccol, float* __restrict__ cval){
  int e = blockIdx.x*256 + threadIdx.x; if (e >= NEDGE) return;
  int p = atomicAdd(&cursor[rows[e]], 1);
  ccol[p] = cols[e]; cval[p] = vals[e];
}

// ---------------- SpMM: f32 out + bf16 shadow ----------------
__global__ __launch_bounds__(256) void k_spmm(const int* __restrict__ rowptr, const int* __restrict__ ccol,
                                              const float* __restrict__ cval, const float* __restrict__ x,
                                              float* __restrict__ out, u16* __restrict__ outb){
  int r = blockIdx.x, c = threadIdx.x;
  int s = rowptr[r], e = rowptr[r+1];
  float acc = 0.f;
  for (int i = s; i < e; ++i)
    acc += cval[i] * x[((size_t)ccol[i] << 8) + c];
  out[((size_t)r << 8) + c] = acc;
  outb[((size_t)r << 8) + c] = f2bu(acc);
}

// ---------------- MFMA GEMM (unchanged) ----------------
template<int RELU, int BIAS, int BF16OUT>
__global__ __launch_bounds__(256) void k_gemm_mfma(const u16* __restrict__ A, const u16* __restrict__ Wt,
                                                   const float* __restrict__ bias, void* __restrict__ Cv,
                                                   int M, int K, int Nc){
  __shared__ u16 Al[128*64];
  __shared__ u16 Bl[128*64];
  const int tid = threadIdx.x;
  const int w  = tid >> 6, l = tid & 63, lr = l & 15, g = l >> 4;
  const int row0 = blockIdx.y*128, col0 = blockIdx.x*128;
  const int wm = (w >> 1)*64, wn = (w & 1)*64;
  const int sm = tid >> 1;
  const int so = (tid & 1)*4;
  float4v acc[4][4] = {};

  for (int k0 = 0; k0 < K; k0 += 64){
    const u16* As = A  + (size_t)(row0 + sm)*K + k0 + so*8;
    const u16* Bs = Wt + (size_t)(col0 + sm)*K + k0 + so*8;
    #pragma unroll
    for (int j = 0; j < 4; ++j){
      int o = so + j;
      int slot = o ^ (sm & 7);
      *(short8v*)(Al + sm*64 + slot*8) = *(const short8v*)(As + j*8);
      *(short8v*)(Bl + sm*64 + slot*8) = *(const short8v*)(Bs + j*8);
    }
    __syncthreads();
    #pragma unroll
    for (int kk = 0; kk < 2; ++kk){
      short8v af[4], bfr[4];
      #pragma unroll
      for (int i = 0; i < 4; ++i){
        int am = wm + 16*i + lr;
        af[i]  = *(const short8v*)(Al + am*64 + (((4*kk + g) ^ (am & 7))*8));
        int bn = wn + 16*i + lr;
        bfr[i] = *(const short8v*)(Bl + bn*64 + (((4*kk + g) ^ (bn & 7))*8));
      }
      #pragma unroll
      for (int mi = 0; mi < 4; ++mi)
        #pragma unroll
        for (int ni = 0; ni < 4; ++ni)
          acc[mi][ni] = mfma16(af[mi], bfr[ni], acc[mi][ni]);
    }
    __syncthreads();
  }

  #pragma unroll
  for (int mi = 0; mi < 4; ++mi){
    #pragma unroll
    for (int ni = 0; ni < 4; ++ni){
      int col = col0 + wn + 16*ni + lr;
      float bv = BIAS ? bias[col] : 0.f;
      #pragma unroll
      for (int j = 0; j < 4; ++j){
        int row = row0 + wm + 16*mi + 4*g + j;
        float v = acc[mi][ni][j] + bv;
        if (RELU) v = fmaxf(v, 0.f);
        if (BF16OUT) ((u16*)Cv)[(size_t)row*Nc + col] = f2bu(v);
        else         ((float*)Cv)[(size_t)row*Nc + col] = v;
      }
    }
  }
}

// ---------------- MFMA flash attention, split-K, swapped QK^T ----------------
// grid (NTOT/64, NH, KSPLIT); 4 waves, wave w owns q rows [qb+16w .. +16).
// S^T = mfma(K, Q): lane (lr,g) holds P[q=lr][kv=16nt+4g+j] — softmax stats
// are per-lane scalars (2 shuffles to reduce across g-groups).
// K frags read directly from global (L2-resident); V double-buffered in LDS.
__global__ __launch_bounds__(256) void k_attn_mfma(const u16* __restrict__ qbf,
                                                   float* __restrict__ op0, float* __restrict__ op1,
                                                   float* __restrict__ mbuf, float* __restrict__ lbuf){
  __shared__ u16 Vt[2][32*64];     // [buf][dh][kv] swizzled
  __shared__ u16 Pl[4][16*64];     // per-wave P [q][kv] swizzled
  __shared__ float Fl[4][16];      // per-wave fac (q-indexed)
  const int h   = blockIdx.y;
  const int ks  = blockIdx.z;
  const int qb  = blockIdx.x * 64;
  const int tid = threadIdx.x;
  const int w   = tid >> 6;
  const int l   = tid & 63;
  const int lr  = l & 15;
  const int g   = l >> 4;
  const int sr  = tid >> 2;
  const int sq  = tid & 3;
  const float SC = 0.17677669529663687f;   // 1/sqrt(32)
  float* opart = ks ? op1 : op0;

  short8v qf = *(const short8v*)(qbf + (size_t)(qb + 16*w + lr)*768 + h*DHD + 8*g);

  float4v oa0 = {0.f,0.f,0.f,0.f}, oa1 = {0.f,0.f,0.f,0.f};
  float mrun = -1e30f, lrun = 0.f;         // per-lane (q = lr), raw domain
  u16* pw = &Pl[w][0];

  // pipeline regs: V tile t, K frags tile t
  const u16* vp = qbf + (size_t)(ks*KVHALF + sr)*768 + 512 + h*DHD + 8*sq;
  const u16* kp = qbf + (size_t)(ks*KVHALF + lr)*768 + 256 + h*DHD + 8*g;
  short8v vreg = *(const short8v*)vp;
  short8v kf0 = *(const short8v*)(kp);
  short8v kf1 = *(const short8v*)(kp + (size_t)16*768);
  short8v kf2 = *(const short8v*)(kp + (size_t)32*768);
  short8v kf3 = *(const short8v*)(kp + (size_t)48*768);

  const int NIT = KVHALF/64;
  for (int t = 0; t < NIT; ++t){
    u16* vt = &Vt[t & 1][0];
    // ---- stage V tile t (cooperative, transposed+swizzled) ----
    #pragma unroll
    for (int j = 0; j < 8; ++j){
      int row  = 8*sq + j;
      int slot = (sr >> 3) ^ j;
      vt[row*64 + slot*8 + (sr & 7)] = (u16)vreg[j];
    }
    __syncthreads();                        // single barrier per iter (dbuf V)
    // ---- prefetch V tile t+1 ----
    vp += (size_t)64*768;
    if (t + 1 < NIT) vreg = *(const short8v*)vp;

    // ---- S^T = K·Q (D: row=kv_local=4g+j, col=q=lr) ----
    float4v s0 = mfma16(kf0, qf, (float4v){0.f,0.f,0.f,0.f});
    float4v s1 = mfma16(kf1, qf, (float4v){0.f,0.f,0.f,0.f});
    float4v s2 = mfma16(kf2, qf, (float4v){0.f,0.f,0.f,0.f});
    float4v s3 = mfma16(kf3, qf, (float4v){0.f,0.f,0.f,0.f});
    // ---- prefetch K frags tile t+1 (L2-resident) ----
    if (t + 1 < NIT){
      const u16* kn = kp + (size_t)(t+1)*64*768;
      kf0 = *(const short8v*)(kn);
      kf1 = *(const short8v*)(kn + (size_t)16*768);
      kf2 = *(const short8v*)(kn + (size_t)32*768);
      kf3 = *(const short8v*)(kn + (size_t)48*768);
    }

    // ---- per-lane softmax stats (q = lr) ----
    float tm = fmaxf(fmaxf(fmaxf(s0[0],s0[1]),fmaxf(s0[2],s0[3])),
              fmaxf(fmaxf(fmaxf(s1[0],s1[1]),fmaxf(s1[2],s1[3])),
              fmaxf(fmaxf(fmaxf(s2[0],s2[1]),fmaxf(s2[2],s2[3])),
                    fmaxf(fmaxf(s3[0],s3[1]),fmaxf(s3[2],s3[3])))));
    tm = fmaxf(tm, __shfl_xor(tm, 16));
    tm = fmaxf(tm, __shfl_xor(tm, 32));
    float mn  = fmaxf(mrun, tm);
    float fac = __expf((mrun - mn)*SC);
    float mns = mn*SC;
    mrun = mn;
    float rs = 0.f;
    #pragma unroll
    for (int j = 0; j < 4; ++j){
      float p0 = __expf(__builtin_fmaf(s0[j], SC, -mns)); s0[j] = p0;
      float p1 = __expf(__builtin_fmaf(s1[j], SC, -mns)); s1[j] = p1;
      float p2 = __expf(__builtin_fmaf(s2[j], SC, -mns)); s2[j] = p2;
      float p3 = __expf(__builtin_fmaf(s3[j], SC, -mns)); s3[j] = p3;
      rs += (p0 + p1) + (p2 + p3);
    }
    rs += __shfl_xor(rs, 16);
    rs += __shfl_xor(rs, 32);
    lrun = lrun*fac + rs;
    if (g == 0) Fl[w][lr] = fac;

    // ---- P -> LDS: one b64 per nt (packed bf16 pairs, consecutive kv) ----
    {
      unsigned int a0 = (unsigned)f2bu(s0[0]) | ((unsigned)f2bu(s0[1]) << 16);
      unsigned int b0 = (unsigned)f2bu(s0[2]) | ((unsigned)f2bu(s0[3]) << 16);
      unsigned int a1 = (unsigned)f2bu(s1[0]) | ((unsigned)f2bu(s1[1]) << 16);
      unsigned int b1 = (unsigned)f2bu(s1[2]) | ((unsigned)f2bu(s1[3]) << 16);
      unsigned int a2 = (unsigned)f2bu(s2[0]) | ((unsigned)f2bu(s2[1]) << 16);
      unsigned int b2 = (unsigned)f2bu(s2[2]) | ((unsigned)f2bu(s2[3]) << 16);
      unsigned int a3 = (unsigned)f2bu(s3[0]) | ((unsigned)f2bu(s3[1]) << 16);
      unsigned int b3 = (unsigned)f2bu(s3[2]) | ((unsigned)f2bu(s3[3]) << 16);
      int gh = g >> 1, gl = 4*(g & 1);
      uint2v* d0 = (uint2v*)(pw + lr*64 + ((0 + gh) ^ (lr & 7))*8 + gl);
      uint2v* d1 = (uint2v*)(pw + lr*64 + ((2 + gh) ^ (lr & 7))*8 + gl);
      uint2v* d2 = (uint2v*)(pw + lr*64 + ((4 + gh) ^ (lr & 7))*8 + gl);
      uint2v* d3 = (uint2v*)(pw + lr*64 + ((6 + gh) ^ (lr & 7))*8 + gl);
      *d0 = (uint2v){a0, b0};
      *d1 = (uint2v){a1, b1};
      *d2 = (uint2v){a2, b2};
      *d3 = (uint2v){a3, b3};
    }

    // ---- rescale O by fac in q=4g+j domain ----
    float fq0 = Fl[w][4*g+0], fq1 = Fl[w][4*g+1], fq2 = Fl[w][4*g+2], fq3 = Fl[w][4*g+3];
    oa0[0]*=fq0; oa0[1]*=fq1; oa0[2]*=fq2; oa0[3]*=fq3;
    oa1[0]*=fq0; oa1[1]*=fq1; oa1[2]*=fq2; oa1[3]*=fq3;

    // ---- O += P V ----
    #pragma unroll
    for (int kk = 0; kk < 2; ++kk){
      int slotp = (4*kk + g) ^ (lr & 7);
      short8v pa = *(const short8v*)(pw + lr*64 + slotp*8);
      short8v v0 = *(const short8v*)(vt + lr*64        + slotp*8);
      short8v v1 = *(const short8v*)(vt + (lr+16)*64   + slotp*8);
      oa0 = mfma16(pa, v0, oa0);
      oa1 = mfma16(pa, v1, oa1);
    }
  }

  // ---- epilogue: unnormalized partial O (D layout: row=q=4g+j, col=dh=lr) ----
  #pragma unroll
  for (int j = 0; j < 4; ++j){
    size_t row = (size_t)(qb + 16*w + 4*g + j);
    opart[row*DIM + h*DHD + lr]      = oa0[j];
    opart[row*DIM + h*DHD + 16 + lr] = oa1[j];
  }
  if (l < 16){
    size_t mi = (size_t)(ks*NH + h)*NTOT + qb + 16*w + lr;
    mbuf[mi] = mrun*SC;
    lbuf[mi] = lrun;
  }
}

// ---------------- split-K merge ----------------
__global__ __launch_bounds__(256) void k_attn_merge(const float* __restrict__ o0, const float* __restrict__ o1,
                                                    const float* __restrict__ mbuf, const float* __restrict__ lbuf,
                                                    u16* __restrict__ obf){
  int i = blockIdx.x*256 + threadIdx.x;
  int r = i >> 8, c = i & 255, h = c >> 5;
  size_t i0 = (size_t)h*NTOT + r;
  size_t i1 = (size_t)(NH + h)*NTOT + r;
  float m0 = mbuf[i0], m1 = mbuf[i1];
  float M  = fmaxf(m0, m1);
  float w0 = __expf(m0 - M), w1 = __expf(m1 - M);
  float L  = w0*lbuf[i0] + w1*lbuf[i1];
  obf[i] = f2bu((w0*o0[i] + w1*o1[i]) / L);
}

// ---------------- fused residual + LayerNorm ----------------
template<int DUAL>
__global__ __launch_bounds__(256) void k_add_ln(const float* __restrict__ a, const float* __restrict__ b,
                                                const float* __restrict__ g, const float* __restrict__ be,
                                                float* __restrict__ out, u16* __restrict__ out2){
  __shared__ float red[4];
  int r = blockIdx.x, c = threadIdx.x;
  float v = a[((size_t)r << 8) + c] + b[((size_t)r << 8) + c];
  float s = v;
  #pragma unroll
  for (int off = 32; off; off >>= 1) s += __shfl_down(s, off);
  if ((c & 63) == 0) red[c >> 6] = s;
  __syncthreads();
  float mean = (red[0]+red[1]+red[2]+red[3]) * (1.f/DIM);
  __syncthreads();
  float d = v - mean;
  float s2 = d*d;
  #pragma unroll
  for (int off = 32; off; off >>= 1) s2 += __shfl_down(s2, off);
  if ((c & 63) == 0) red[c >> 6] = s2;
  __syncthreads();
  float var = (red[0]+red[1]+red[2]+red[3]) * (1.f/DIM);
  float rv = d * rsqrtf(var + LNEPS) * g[c] + be[c];
  out[((size_t)r << 8) + c] = rv;
  if (DUAL) out2[((size_t)r << 8) + c] = f2bu(rv);
}

// ---------------- cur += x2; total += cur ----------------
__global__ __launch_bounds__(256) void k_update(const float* __restrict__ x2, float* __restrict__ cur,
                                                float* __restrict__ tot){
  int i = blockIdx.x*256 + threadIdx.x;
  float c = cur[i] + x2[i];
  cur[i] = c;
  tot[i] += c;
}

// ---------------- output ----------------
__global__ __launch_bounds__(256) void k_out(const float* __restrict__ tot, float* __restrict__ out){
  int i = blockIdx.x*256 + threadIdx.x;
  float v = tot[i];
  out[i] = v;
  out[NTOT*DIM + i] = v;
}

extern "C" void kernel_launch(void* const* d_in, const int* in_sizes, int n_in,
                              void* d_out, int out_size, void* d_ws, size_t ws_size,
                              hipStream_t stream){
  const int*   adj_row = (const int*)  d_in[0];
  const int*   adj_col = (const int*)  d_in[1];
  const float* adj_val = (const float*)d_in[2];
  const float* pe   = (const float*)d_in[3];
  const float* ae   = (const float*)d_in[4];
  const float* qe   = (const float*)d_in[5];
  const float* Wqkv = (const float*)d_in[6];
  const float* Wo   = (const float*)d_in[7];
  const float* W1   = (const float*)d_in[8];
  const float* b1   = (const float*)d_in[9];
  const float* W2   = (const float*)d_in[10];
  const float* b2   = (const float*)d_in[11];
  const float* g1   = (const float*)d_in[12];
  const float* be1  = (const float*)d_in[13];
  const float* g2   = (const float*)d_in[14];
  const float* be2  = (const float*)d_in[15];
  float* out = (float*)d_out;

  // ---- workspace (~36.7 MB) ----
  char* w = (char*)d_ws;
  float* cur  = (float*)w; w += (size_t)NTOT*DIM*4;
  float* tot  = (float*)w; w += (size_t)NTOT*DIM*4;
  float* tf   = (float*)w; w += (size_t)NTOT*DIM*4;
  float* pbuf = (float*)w; w += (size_t)NTOT*DIM*4;        // proj/ffn2 out; attn partial 0
  float* x1   = (float*)w; w += (size_t)NTOT*DIM*4;        // x1; attn partial 1
  u16* tbf    = (u16*)w;   w += (size_t)NTOT*DIM*2;        // spmm bf16; attn m/l
  u16* obf    = (u16*)w;   w += (size_t)NTOT*DIM*2;
  u16* x1b    = (u16*)w;   w += (size_t)NTOT*DIM*2;
  u16* hq     = (u16*)w;   w += (size_t)NTOT*FFD*2;        // qbf ∪ h
  u16* wqkvt  = (u16*)w;   w += (size_t)768*256*2;
  u16* wot    = (u16*)w;   w += (size_t)256*256*2;
  u16* w1t    = (u16*)w;   w += (size_t)1024*256*2;
  u16* w2t    = (u16*)w;   w += (size_t)256*1024*2;
  int* rowptr = (int*)w;   w += (size_t)(NTOT+1)*4;
  int* cnt    = (int*)w;   w += (size_t)NTOT*4;
  int* cursor = (int*)w;   w += (size_t)NTOT*4;
  int* ccol   = (int*)w;   w += (size_t)NEDGE*4;
  float* cval = (float*)w; w += (size_t)NEDGE*4;
  u16* qbf = hq;
  float* mbuf = (float*)tbf;
  float* lbuf = mbuf + (size_t)KSPLIT*NH*NTOT;

  k_zero<<<16, 256, 0, stream>>>(cnt, NTOT);
  k_embed<<<NTOT, 256, 0, stream>>>(pe, ae, qe, cur, tot);
  k_hist<<<NEDGE/256, 256, 0, stream>>>(adj_row, cnt);
  k_scan<<<1, 64, 0, stream>>>(cnt, rowptr, cursor);
  k_scatter<<<NEDGE/256, 256, 0, stream>>>(adj_row, adj_col, adj_val, cursor, ccol, cval);
  k_wconv<<<768,  256, 0, stream>>>(Wqkv, wqkvt, 256, 768);
  k_wconv<<<256,  256, 0, stream>>>(Wo,   wot,   256, 256);
  k_wconv<<<1024, 256, 0, stream>>>(W1,   w1t,   256, 1024);
  k_wconv<<<256,  256, 0, stream>>>(W2,   w2t,  1024, 256);

  for (int blk = 0; blk < 3; ++blk){
    k_spmm<<<NTOT, 256, 0, stream>>>(rowptr, ccol, cval, cur, tf, tbf);
    k_gemm_mfma<0,0,1><<<dim3(768/128, NTOT/128), 256, 0, stream>>>(tbf, wqkvt, nullptr, qbf, NTOT, 256, 768);
    k_attn_mfma<<<dim3(NTOT/64, NH, KSPLIT), 256, 0, stream>>>(qbf, pbuf, x1, mbuf, lbuf);
    k_attn_merge<<<NTOT*DIM/256, 256, 0, stream>>>(pbuf, x1, mbuf, lbuf, obf);
    k_gemm_mfma<0,0,0><<<dim3(256/128, NTOT/128), 256, 0, stream>>>(obf, wot, nullptr, pbuf, NTOT, 256, 256);
    k_add_ln<1><<<NTOT, 256, 0, stream>>>(tf, pbuf, g1, be1, x1, x1b);
    k_gemm_mfma<1,1,1><<<dim3(1024/128, NTOT/128), 256, 0, stream>>>(x1b, w1t, b1, hq, NTOT, 256, 1024);
    k_gemm_mfma<0,1,0><<<dim3(256/128, NTOT/128), 256, 0, stream>>>(hq, w2t, b2, pbuf, NTOT, 1024, 256);
    k_add_ln<0><<<NTOT, 256, 0, stream>>>(x1, pbuf, g2, be2, tf, nullptr);
    k_update<<<NTOT, 256, 0, stream>>>(tf, cur, tot);
  }
  k_out<<<NTOT, 256, 0, stream>>>(tot, out);
}